// Round 1
// baseline (2228.212 us; speedup 1.0000x reference)
//
#include <hip/hip_runtime.h>

using u8 = unsigned char;

// ---------------- mask init: m = (maskraw == 0) ----------------
__global__ void mask_init_k(const int* __restrict__ mr, u8* __restrict__ m, int N) {
    int i = blockIdx.x * blockDim.x + threadIdx.x;
    if (i < N) m[i] = (mr[i] == 0) ? 1 : 0;
}

// ---------------- mask pool 2x2x2 (logical OR), full batch ----------------
template <int SO>
__global__ void pool_k(const u8* __restrict__ mi, u8* __restrict__ mo) {
    const int N = 128 * SO * SO * SO;
    constexpr int SI = 2 * SO;
    int v = blockIdx.x * blockDim.x + threadIdx.x;
    if (v >= N) return;
    int t = v;
    int x = t % SO; t /= SO;
    int y = t % SO; t /= SO;
    int z = t % SO;
    int n = t / SO;
    u8 m = 0;
    for (int kd = 0; kd < 2; kd++)
        for (int kh = 0; kh < 2; kh++)
            for (int kw = 0; kw < 2; kw++)
                m |= mi[((n * SI + 2 * z + kd) * SI + 2 * y + kh) * SI + 2 * x + kw];
    mo[v] = m;
}

// ================= active-group list builders (32^3, groups of 4 consecutive x) =================
// group g: xb=(g&7)*4, y=(g>>3)&31, z=(g>>8)&31, n=g>>13, vbase=((g>>3)<<5)+xb

// group active iff any of its 4 mask bytes set (mask buffer 4-byte aligned)
__global__ void build_glist_k(const u8* __restrict__ m, int* __restrict__ list,
                              int* __restrict__ cnt) {
    const int NG = 128 * 32768 / 4;
    int g = blockIdx.x * blockDim.x + threadIdx.x;
    if (g >= NG) return;
    if (*(const unsigned*)(m + ((size_t)g << 2))) {
        int i = atomicAdd(cnt, 1);
        list[i] = g;
    }
}

// group active iff either of its two parent (16^3) mask bytes set — matches conv3s4 gate
__global__ void build_slist_k(const u8* __restrict__ mD16, int* __restrict__ list,
                              int* __restrict__ cnt) {
    const int NG = 128 * 32768 / 4;
    int g = blockIdx.x * blockDim.x + threadIdx.x;
    if (g >= NG) return;
    int xb = (g & 7) << 2;
    int y = (g >> 3) & 31;
    int z = (g >> 8) & 31;
    int n = g >> 13;
    int pbase = ((n * 16 + (z >> 1)) * 16 + (y >> 1)) * 16 + (xb >> 1);
    if (*(const unsigned short*)(mD16 + pbase)) {
        int i = atomicAdd(cnt, 1);
        list[i] = g;
    }
}

// ================= 32^3 XPT=4 list-driven kernels =================

// ---------------- prepare conv 1->4, k=3, masked input+output (no prezero needed:
// consumers bn_reduce/convbn4c are mask-checked) ----------------
__global__ void prep4c_k(const float* __restrict__ vox, const u8* __restrict__ m,
                         const float* __restrict__ wp, float* __restrict__ out,
                         const int* __restrict__ list, const int* __restrict__ cnt) {
    int i = blockIdx.x * blockDim.x + threadIdx.x;
    if (i >= *cnt) return;
    int g = list[i];
    int xb = (g & 7) << 2;
    int y = (g >> 3) & 31;
    int z = (g >> 8) & 31;
    int n = g >> 13;
    int vbase = ((g >> 3) << 5) + xb;
    u8 om[4];
#pragma unroll
    for (int j = 0; j < 4; j++) om[j] = m[vbase + j];
    float acc[4][4];
#pragma unroll
    for (int j = 0; j < 4; j++)
#pragma unroll
        for (int co = 0; co < 4; co++) acc[j][co] = 0.f;
    for (int kd = 0; kd < 3; kd++) {
        int zz = z + kd - 1; if ((unsigned)zz >= 32u) continue;
        for (int kh = 0; kh < 3; kh++) {
            int yy = y + kh - 1; if ((unsigned)yy >= 32u) continue;
            int base = ((n * 32 + zz) * 32 + yy) * 32;
            float col[6];
#pragma unroll
            for (int c = 0; c < 6; c++) {
                int xx = xb - 1 + c;
                col[c] = ((unsigned)xx < 32u && m[base + xx]) ? vox[base + xx] : 0.f;
            }
            const float* wrow = wp + ((kd * 3 + kh) * 3) * 4;
#pragma unroll
            for (int kw = 0; kw < 3; kw++) {
                const float* wt = wrow + kw * 4;
#pragma unroll
                for (int j = 0; j < 4; j++) {
                    float xv = col[j + kw];
#pragma unroll
                    for (int co = 0; co < 4; co++) acc[j][co] += xv * wt[co];
                }
            }
        }
    }
#pragma unroll
    for (int j = 0; j < 4; j++)
#pragma unroll
        for (int co = 0; co < 4; co++)
            out[(size_t)(vbase + j) * 4 + co] = om[j] ? acc[j][co] : 0.f;
}

// ---------------- conv k=3, 4->4, BN(affine+ReLU+mask) on load, list-driven
// (output pre-zeroed: down_k reads unmasked) ----------------
__global__ void convbn4c_k(const float* __restrict__ in, const float* __restrict__ w,
                           const u8* __restrict__ mask, const double* __restrict__ params,
                           float* __restrict__ out,
                           const int* __restrict__ list, const int* __restrict__ cnt) {
    int i = blockIdx.x * blockDim.x + threadIdx.x;
    if (i >= *cnt) return;
    int g = list[i];
    int xb = (g & 7) << 2;
    int y = (g >> 3) & 31;
    int z = (g >> 8) & 31;
    int n = g >> 13;
    int vbase = ((g >> 3) << 5) + xb;
    u8 om[4];
#pragma unroll
    for (int j = 0; j < 4; j++) om[j] = mask[vbase + j];
    float sc[4], sh[4];
#pragma unroll
    for (int c = 0; c < 4; c++) { sc[c] = (float)params[c]; sh[c] = (float)params[4 + c]; }
    float acc[4][4];
#pragma unroll
    for (int j = 0; j < 4; j++)
#pragma unroll
        for (int co = 0; co < 4; co++) acc[j][co] = 0.f;
    for (int kd = 0; kd < 3; kd++) {
        int zz = z + kd - 1; if ((unsigned)zz >= 32u) continue;
        for (int kh = 0; kh < 3; kh++) {
            int yy = y + kh - 1; if ((unsigned)yy >= 32u) continue;
            int base = ((n * 32 + zz) * 32 + yy) * 32;
            float col[6][4];
#pragma unroll
            for (int c = 0; c < 6; c++) {
                int xx = xb - 1 + c;
                bool valid = ((unsigned)xx < 32u) && mask[base + xx];
                const float* ip = in + (size_t)(base + xx) * 4;
#pragma unroll
                for (int ci = 0; ci < 4; ci++)
                    col[c][ci] = valid ? fmaxf(ip[ci] * sc[ci] + sh[ci], 0.f) : 0.f;
            }
            const float* wrow = w + ((kd * 3 + kh) * 3) * 16;
#pragma unroll
            for (int kw = 0; kw < 3; kw++) {
                const float* wt = wrow + kw * 16;
#pragma unroll
                for (int j = 0; j < 4; j++) {
#pragma unroll
                    for (int ci = 0; ci < 4; ci++) {
                        float xv = col[j + kw][ci];
#pragma unroll
                        for (int co = 0; co < 4; co++) acc[j][co] += xv * wt[ci * 4 + co];
                    }
                }
            }
        }
    }
#pragma unroll
    for (int j = 0; j < 4; j++)
#pragma unroll
        for (int co = 0; co < 4; co++)
            out[(size_t)(vbase + j) * 4 + co] = om[j] ? acc[j][co] : 0.f;
}

// ---------------- plain conv 4->4, k=4 pad(1,2), list-driven (output pre-zeroed) ----------------
__global__ void conv4x4c_k(const float* __restrict__ in, const float* __restrict__ w,
                           const u8* __restrict__ outmask, float* __restrict__ out,
                           const int* __restrict__ list, const int* __restrict__ cnt) {
    constexpr int K = 4;
    constexpr int PLO = (K - 1) / 2;
    constexpr int NC = K + 3;
    int i = blockIdx.x * blockDim.x + threadIdx.x;
    if (i >= *cnt) return;
    int g = list[i];
    int xb = (g & 7) << 2;
    int y = (g >> 3) & 31;
    int z = (g >> 8) & 31;
    int n = g >> 13;
    int vbase = ((g >> 3) << 5) + xb;
    u8 om[4];
#pragma unroll
    for (int j = 0; j < 4; j++) om[j] = outmask[vbase + j];
    float acc[4][4];
#pragma unroll
    for (int j = 0; j < 4; j++)
#pragma unroll
        for (int co = 0; co < 4; co++) acc[j][co] = 0.f;
    for (int kd = 0; kd < K; kd++) {
        int zz = z + kd - PLO; if ((unsigned)zz >= 32u) continue;
        for (int kh = 0; kh < K; kh++) {
            int yy = y + kh - PLO; if ((unsigned)yy >= 32u) continue;
            int base = ((n * 32 + zz) * 32 + yy) * 32;
            float col[NC][4];
#pragma unroll
            for (int c = 0; c < NC; c++) {
                int xx = xb - PLO + c;
                bool valid = ((unsigned)xx < 32u);
                const float* ip = in + (size_t)(base + xx) * 4;
#pragma unroll
                for (int ci = 0; ci < 4; ci++) col[c][ci] = valid ? ip[ci] : 0.f;
            }
            const float* wrow = w + ((kd * K + kh) * K) * 16;
#pragma unroll
            for (int kw = 0; kw < K; kw++) {
                const float* wt = wrow + kw * 16;
#pragma unroll
                for (int j = 0; j < 4; j++) {
#pragma unroll
                    for (int ci = 0; ci < 4; ci++) {
                        float xv = col[j + kw][ci];
#pragma unroll
                        for (int co = 0; co < 4; co++) acc[j][co] += xv * wt[ci * 4 + co];
                    }
                }
            }
        }
    }
#pragma unroll
    for (int j = 0; j < 4; j++)
#pragma unroll
        for (int co = 0; co < 4; co++)
            out[(size_t)(vbase + j) * 4 + co] = om[j] ? acc[j][co] : 0.f;
}

// ---------------- conv k=3 4->4 + fused sparsify (fp64 gate), list-driven
// (out + nmask pre-zeroed) ----------------
__global__ void conv3s4c_k(const float* __restrict__ in, const float* __restrict__ w,
                           const u8* __restrict__ pmask, u8* __restrict__ nmask,
                           float* __restrict__ out, double delta,
                           const int* __restrict__ list, const int* __restrict__ cnt) {
    int i = blockIdx.x * blockDim.x + threadIdx.x;
    if (i >= *cnt) return;
    int g = list[i];
    int xb = (g & 7) << 2;
    int y = (g >> 3) & 31;
    int z = (g >> 8) & 31;
    int n = g >> 13;
    int vbase = ((g >> 3) << 5) + xb;
    int pbase = ((n * 16 + (z >> 1)) * 16 + (y >> 1)) * 16 + (xb >> 1);
    u8 pm[4];
    pm[0] = pm[1] = pmask[pbase];
    pm[2] = pm[3] = pmask[pbase + 1];
    double acc0[4], asum[4];
    float accf[4][4];
#pragma unroll
    for (int j = 0; j < 4; j++) {
        acc0[j] = 0.0; asum[j] = 0.0;
#pragma unroll
        for (int co = 0; co < 4; co++) accf[j][co] = 0.f;
    }
    for (int kd = 0; kd < 3; kd++) {
        int zz = z + kd - 1; if ((unsigned)zz >= 32u) continue;
        for (int kh = 0; kh < 3; kh++) {
            int yy = y + kh - 1; if ((unsigned)yy >= 32u) continue;
            int base = ((n * 32 + zz) * 32 + yy) * 32;
            float col[6][4];
#pragma unroll
            for (int c = 0; c < 6; c++) {
                int xx = xb - 1 + c;
                bool valid = ((unsigned)xx < 32u);
                const float* ip = in + (size_t)(base + xx) * 4;
#pragma unroll
                for (int ci = 0; ci < 4; ci++) col[c][ci] = valid ? ip[ci] : 0.f;
            }
            const float* wrow = w + ((kd * 3 + kh) * 3) * 16;
#pragma unroll
            for (int kw = 0; kw < 3; kw++) {
                const float* wt = wrow + kw * 16;
#pragma unroll
                for (int j = 0; j < 4; j++) {
#pragma unroll
                    for (int ci = 0; ci < 4; ci++) {
                        float xv = col[j + kw][ci];
                        double term = (double)xv * (double)wt[ci * 4 + 0];
                        acc0[j] += term;
                        asum[j] += fabs(term);
#pragma unroll
                        for (int co = 1; co < 4; co++) accf[j][co] += xv * wt[ci * 4 + co];
                    }
                }
            }
        }
    }
#pragma unroll
    for (int j = 0; j < 4; j++) {
        u8 nm = (pm[j] && (acc0[j] > -delta * asum[j])) ? 1 : 0;
        nmask[vbase + j] = nm;
        out[(size_t)(vbase + j) * 4 + 0] = nm ? (float)acc0[j] : 0.f;
#pragma unroll
        for (int co = 1; co < 4; co++) out[(size_t)(vbase + j) * 4 + co] = nm ? accf[j][co] : 0.f;
    }
}

// ---------------- final output conv k=3, 4->1, list-driven (output pre-zeroed) ----------------
__global__ void outconv4c_k(const float* __restrict__ in, const float* __restrict__ w,
                            const u8* __restrict__ mask, float* __restrict__ out,
                            const int* __restrict__ list, const int* __restrict__ cnt) {
    int i = blockIdx.x * blockDim.x + threadIdx.x;
    if (i >= *cnt) return;
    int g = list[i];
    int xb = (g & 7) << 2;
    int y = (g >> 3) & 31;
    int z = (g >> 8) & 31;
    int n = g >> 13;
    int vbase = ((g >> 3) << 5) + xb;
    u8 om[4];
#pragma unroll
    for (int j = 0; j < 4; j++) om[j] = mask[vbase + j];
    float acc[4] = {0.f, 0.f, 0.f, 0.f};
    for (int kd = 0; kd < 3; kd++) {
        int zz = z + kd - 1; if ((unsigned)zz >= 32u) continue;
        for (int kh = 0; kh < 3; kh++) {
            int yy = y + kh - 1; if ((unsigned)yy >= 32u) continue;
            int base = ((n * 32 + zz) * 32 + yy) * 32;
            float col[6][4];
#pragma unroll
            for (int c = 0; c < 6; c++) {
                int xx = xb - 1 + c;
                bool valid = ((unsigned)xx < 32u);
                const float* ip = in + (size_t)(base + xx) * 4;
#pragma unroll
                for (int ci = 0; ci < 4; ci++) col[c][ci] = valid ? ip[ci] : 0.f;
            }
            const float* wrow = w + ((kd * 3 + kh) * 3) * 4;
#pragma unroll
            for (int kw = 0; kw < 3; kw++) {
                const float* wt = wrow + kw * 4;
#pragma unroll
                for (int j = 0; j < 4; j++) {
#pragma unroll
                    for (int ci = 0; ci < 4; ci++) acc[j] += col[j + kw][ci] * wt[ci];
                }
            }
        }
    }
#pragma unroll
    for (int j = 0; j < 4; j++) out[vbase + j] = om[j] ? acc[j] : 0.f;
}

// ================= generic kernels for 16^3 / 8^3 stages (unchanged) =================

template <int K, int CIN, int COUT, int S>
__global__ void conv_k(const float* __restrict__ in, const float* __restrict__ w,
                       const u8* __restrict__ outmask, float* __restrict__ out) {
    const int N = 128 * S * S * S;
    int v = blockIdx.x * blockDim.x + threadIdx.x;
    if (v >= N) return;
    if (!outmask[v]) {
#pragma unroll
        for (int co = 0; co < COUT; co++) out[(size_t)v * COUT + co] = 0.f;
        return;
    }
    int t = v;
    int x = t % S; t /= S;
    int y = t % S; t /= S;
    int z = t % S;
    int n = t / S;
    float acc[COUT];
#pragma unroll
    for (int co = 0; co < COUT; co++) acc[co] = 0.f;
    constexpr int PLO = (K - 1) / 2;
    for (int kd = 0; kd < K; kd++) {
        int zz = z + kd - PLO; if ((unsigned)zz >= (unsigned)S) continue;
        for (int kh = 0; kh < K; kh++) {
            int yy = y + kh - PLO; if ((unsigned)yy >= (unsigned)S) continue;
            for (int kw = 0; kw < K; kw++) {
                int xx = x + kw - PLO; if ((unsigned)xx >= (unsigned)S) continue;
                int sv = ((n * S + zz) * S + yy) * S + xx;
                const float* ip = in + (size_t)sv * CIN;
                const float* wpk = w + ((kd * K + kh) * K + kw) * CIN * COUT;
#pragma unroll
                for (int ci = 0; ci < CIN; ci++) {
                    float xv = ip[ci];
#pragma unroll
                    for (int co = 0; co < COUT; co++) acc[co] += xv * wpk[ci * COUT + co];
                }
            }
        }
    }
#pragma unroll
    for (int co = 0; co < COUT; co++) out[(size_t)v * COUT + co] = acc[co];
}

template <int CIN, int COUT, int S>
__global__ void convbn_k(const float* __restrict__ in, const float* __restrict__ w,
                         const u8* __restrict__ mask, const double* __restrict__ params,
                         float* __restrict__ out) {
    const int N = 128 * S * S * S;
    int v = blockIdx.x * blockDim.x + threadIdx.x;
    if (v >= N) return;
    if (!mask[v]) {
#pragma unroll
        for (int co = 0; co < COUT; co++) out[(size_t)v * COUT + co] = 0.f;
        return;
    }
    int t = v;
    int x = t % S; t /= S;
    int y = t % S; t /= S;
    int z = t % S;
    int n = t / S;
    float sc[CIN], sh[CIN];
#pragma unroll
    for (int c = 0; c < CIN; c++) { sc[c] = (float)params[c]; sh[c] = (float)params[CIN + c]; }
    float acc[COUT];
#pragma unroll
    for (int co = 0; co < COUT; co++) acc[co] = 0.f;
    for (int kd = 0; kd < 3; kd++) {
        int zz = z + kd - 1; if ((unsigned)zz >= (unsigned)S) continue;
        for (int kh = 0; kh < 3; kh++) {
            int yy = y + kh - 1; if ((unsigned)yy >= (unsigned)S) continue;
            for (int kw = 0; kw < 3; kw++) {
                int xx = x + kw - 1; if ((unsigned)xx >= (unsigned)S) continue;
                int sv = ((n * S + zz) * S + yy) * S + xx;
                if (!mask[sv]) continue;
                const float* ip = in + (size_t)sv * CIN;
                const float* wpk = w + ((kd * 3 + kh) * 3 + kw) * CIN * COUT;
#pragma unroll
                for (int ci = 0; ci < CIN; ci++) {
                    float yv = fmaxf(ip[ci] * sc[ci] + sh[ci], 0.f);
#pragma unroll
                    for (int co = 0; co < COUT; co++) acc[co] += yv * wpk[ci * COUT + co];
                }
            }
        }
    }
#pragma unroll
    for (int co = 0; co < COUT; co++) out[(size_t)v * COUT + co] = acc[co];
}

template <int CIN, int COUT, int S>
__global__ void conv3s_k(const float* __restrict__ in, const float* __restrict__ w,
                         const u8* __restrict__ pmask, u8* __restrict__ nmask,
                         float* __restrict__ out, double delta) {
    const int N = 128 * S * S * S;
    constexpr int SP = S / 2;
    int v = blockIdx.x * blockDim.x + threadIdx.x;
    if (v >= N) return;
    int t = v;
    int x = t % S; t /= S;
    int y = t % S; t /= S;
    int z = t % S;
    int n = t / S;
    int pidx = ((n * SP + (z >> 1)) * SP + (y >> 1)) * SP + (x >> 1);
    if (!pmask[pidx]) {
        nmask[v] = 0;
#pragma unroll
        for (int co = 0; co < COUT; co++) out[(size_t)v * COUT + co] = 0.f;
        return;
    }
    double acc0 = 0.0, asum = 0.0;
    float acc[COUT];
#pragma unroll
    for (int co = 0; co < COUT; co++) acc[co] = 0.f;
    for (int kd = 0; kd < 3; kd++) {
        int zz = z + kd - 1; if ((unsigned)zz >= (unsigned)S) continue;
        for (int kh = 0; kh < 3; kh++) {
            int yy = y + kh - 1; if ((unsigned)yy >= (unsigned)S) continue;
            for (int kw = 0; kw < 3; kw++) {
                int xx = x + kw - 1; if ((unsigned)xx >= (unsigned)S) continue;
                int sv = ((n * S + zz) * S + yy) * S + xx;
                const float* ip = in + (size_t)sv * CIN;
                const float* wpk = w + ((kd * 3 + kh) * 3 + kw) * CIN * COUT;
#pragma unroll
                for (int ci = 0; ci < CIN; ci++) {
                    float xv = ip[ci];
                    double term = (double)xv * (double)wpk[ci * COUT + 0];
                    acc0 += term;
                    asum += fabs(term);
#pragma unroll
                    for (int co = 1; co < COUT; co++) acc[co] += xv * wpk[ci * COUT + co];
                }
            }
        }
    }
    u8 nm = (acc0 > -delta * asum) ? 1 : 0;
    nmask[v] = nm;
    out[(size_t)v * COUT + 0] = nm ? (float)acc0 : 0.f;
#pragma unroll
    for (int co = 1; co < COUT; co++) out[(size_t)v * COUT + co] = nm ? acc[co] : 0.f;
}

template <int CIN, int COUT, int SO>
__global__ void down_k(const float* __restrict__ in, const float* __restrict__ w,
                       const u8* __restrict__ outmask, float* __restrict__ out) {
    const int N = 128 * SO * SO * SO;
    constexpr int SI = 2 * SO;
    int v = blockIdx.x * blockDim.x + threadIdx.x;
    if (v >= N) return;
    if (!outmask[v]) {
#pragma unroll
        for (int co = 0; co < COUT; co++) out[(size_t)v * COUT + co] = 0.f;
        return;
    }
    int t = v;
    int x = t % SO; t /= SO;
    int y = t % SO; t /= SO;
    int z = t % SO;
    int n = t / SO;
    float acc[COUT];
#pragma unroll
    for (int co = 0; co < COUT; co++) acc[co] = 0.f;
    for (int kd = 0; kd < 2; kd++)
        for (int kh = 0; kh < 2; kh++)
            for (int kw = 0; kw < 2; kw++) {
                int sv = ((n * SI + 2 * z + kd) * SI + 2 * y + kh) * SI + 2 * x + kw;
                const float* ip = in + (size_t)sv * CIN;
                const float* wpk = w + ((kd * 2 + kh) * 2 + kw) * CIN * COUT;
#pragma unroll
                for (int ci = 0; ci < CIN; ci++) {
                    float xv = ip[ci];
#pragma unroll
                    for (int co = 0; co < COUT; co++) acc[co] += xv * wpk[ci * COUT + co];
                }
            }
#pragma unroll
    for (int co = 0; co < COUT; co++) out[(size_t)v * COUT + co] = acc[co];
}

template <int CIN, int COUT, int SI>
__global__ void upbn_k(const float* __restrict__ in, const float* __restrict__ w,
                       const u8* __restrict__ inmask, const double* __restrict__ params,
                       float* __restrict__ out) {
    constexpr int SO = 2 * SI;
    const int N = 128 * SO * SO * SO;
    int v = blockIdx.x * blockDim.x + threadIdx.x;
    if (v >= N) return;
    int t = v;
    int x = t % SO; t /= SO;
    int y = t % SO; t /= SO;
    int z = t % SO;
    int n = t / SO;
    int sv = ((n * SI + (z >> 1)) * SI + (y >> 1)) * SI + (x >> 1);
    if (!inmask[sv]) {
#pragma unroll
        for (int co = 0; co < COUT; co++) out[(size_t)v * COUT + co] = 0.f;
        return;
    }
    int tap = ((1 - (z & 1)) * 2 + (1 - (y & 1))) * 2 + (1 - (x & 1));
    const float* wpk = w + tap * CIN * COUT;
    const float* ip = in + (size_t)sv * CIN;
    float acc[COUT];
#pragma unroll
    for (int co = 0; co < COUT; co++) acc[co] = 0.f;
#pragma unroll
    for (int ci = 0; ci < CIN; ci++) {
        float yv = fmaxf(ip[ci] * (float)params[ci] + (float)params[CIN + ci], 0.f);
#pragma unroll
        for (int co = 0; co < COUT; co++) acc[co] += yv * wpk[ci * COUT + co];
    }
#pragma unroll
    for (int co = 0; co < COUT; co++) out[(size_t)v * COUT + co] = acc[co];
}

// ---------------- BN masked reduce, DETERMINISTIC two-pass: per-block partials ----------------
template <int C>
__global__ void bn_reduce_k(const float* __restrict__ x, const u8* __restrict__ m, int N,
                            double* __restrict__ partial) {
    double cnt = 0.0, sx[C], s2[C];
#pragma unroll
    for (int c = 0; c < C; c++) { sx[c] = 0.0; s2[c] = 0.0; }
    int stride = gridDim.x * blockDim.x;
    for (int v = blockIdx.x * blockDim.x + threadIdx.x; v < N; v += stride) {
        if (!m[v]) continue;
        cnt += 1.0;
#pragma unroll
        for (int c = 0; c < C; c++) {
            double xv = (double)x[(size_t)v * C + c];
            sx[c] += xv;
            s2[c] += xv * xv;
        }
    }
#pragma unroll
    for (int off = 32; off > 0; off >>= 1) {
        cnt += __shfl_down(cnt, off, 64);
#pragma unroll
        for (int c = 0; c < C; c++) {
            sx[c] += __shfl_down(sx[c], off, 64);
            s2[c] += __shfl_down(s2[c], off, 64);
        }
    }
    __shared__ double sbuf[4][2 * C + 1];
    int wave = threadIdx.x >> 6;
    if ((threadIdx.x & 63) == 0) {
        sbuf[wave][0] = cnt;
#pragma unroll
        for (int c = 0; c < C; c++) {
            sbuf[wave][1 + c] = sx[c];
            sbuf[wave][1 + C + c] = s2[c];
        }
    }
    __syncthreads();
    if (threadIdx.x == 0) {
        double* p = partial + (size_t)blockIdx.x * (2 * C + 1);
        double tcnt = 0.0;
        for (int wv = 0; wv < 4; wv++) tcnt += sbuf[wv][0];
        p[0] = tcnt;
#pragma unroll
        for (int c = 0; c < C; c++) {
            double a = 0.0, b = 0.0;
            for (int wv = 0; wv < 4; wv++) { a += sbuf[wv][1 + c]; b += sbuf[wv][1 + C + c]; }
            p[1 + c] = a;
            p[1 + C + c] = b;
        }
    }
}

// ---------------- BN finalize: fixed-order sum of block partials ----------------
template <int C>
__global__ void bn_final_k(const double* __restrict__ partial, int nblocks,
                           const float* __restrict__ g, const float* __restrict__ b,
                           double* __restrict__ params) {
    int c = threadIdx.x;
    if (c >= C) return;
    double cnt = 0.0, sx = 0.0, s2 = 0.0;
    for (int bk = 0; bk < nblocks; bk++) {
        const double* p = partial + (size_t)bk * (2 * C + 1);
        cnt += p[0];
        sx += p[1 + c];
        s2 += p[1 + C + c];
    }
    if (cnt < 1.0) cnt = 1.0;
    double mean = sx / cnt;
    double var = s2 / cnt - mean * mean;
    double sc = (double)g[c] / sqrt(var + 1e-4);
    params[c] = sc;
    params[C + c] = (double)b[c] - mean * sc;
}

// ---------------- hidden: NDHWC (4^3, 32ch) -> NCDHW flat ----------------
__global__ void hidden_k(const float* __restrict__ x, float* __restrict__ out) {
    int i = blockIdx.x * blockDim.x + threadIdx.x;
    if (i >= 128 * 2048) return;
    int b = i >> 11;
    int r = i & 2047;
    int c = r >> 6;
    int s = r & 63;
    int d = s >> 4;
    int h = (s >> 2) & 3;
    int w = s & 3;
    out[i] = x[((((b * 4 + d) * 4 + h) * 4 + w) << 5) + c];
}

extern "C" void kernel_launch(void* const* d_in, const int* in_sizes, int n_in,
                              void* d_out, int out_size, void* d_ws, size_t ws_size,
                              hipStream_t stream) {
    const float* vox = (const float*)d_in[0];
    const int* mraw = (const int*)d_in[1];
    const float* wp = (const float*)d_in[2];
    const float* g_e0 = (const float*)d_in[3];
    const float* b_e0 = (const float*)d_in[4];
    const float* ws_e0 = (const float*)d_in[5];
    const float* wd_e0 = (const float*)d_in[6];
    const float* g_e1 = (const float*)d_in[7];
    const float* b_e1 = (const float*)d_in[8];
    const float* ws_e1 = (const float*)d_in[9];
    const float* wd_e1 = (const float*)d_in[10];
    const float* g_e2 = (const float*)d_in[11];
    const float* b_e2 = (const float*)d_in[12];
    const float* ws_e2 = (const float*)d_in[13];
    const float* wd_e2 = (const float*)d_in[14];
    const float* g_d0 = (const float*)d_in[15];
    const float* b_d0 = (const float*)d_in[16];
    const float* wu_d0 = (const float*)d_in[17];
    const float* ws3_d0 = (const float*)d_in[18];
    const float* ws4_d0 = (const float*)d_in[19];
    const float* g_d1 = (const float*)d_in[20];
    const float* b_d1 = (const float*)d_in[21];
    const float* wu_d1 = (const float*)d_in[22];
    const float* ws3_d1 = (const float*)d_in[23];
    const float* ws4_d1 = (const float*)d_in[24];
    const float* g_d2 = (const float*)d_in[25];
    const float* b_d2 = (const float*)d_in[26];
    const float* wu_d2 = (const float*)d_in[27];
    const float* ws3_d2 = (const float*)d_in[28];
    const float* ws4_d2 = (const float*)d_in[29];
    const float* wo = (const float*)d_in[30];
    float* out = (float*)d_out;

    // ---- workspace: fp32 tensors + fp64 partials/params + u8 masks (~153 MB) ----
    float* wsf = (float*)d_ws;
    size_t offf = 0;
    auto allocf = [&](size_t n) { float* p = wsf + offf; offf += n; return p; };
    float* R1 = allocf(16777216);
    float* R2 = allocf(16777216);
    float* S1 = allocf(1048576);
    float* S2 = allocf(1048576);
    float* T = allocf(262144);
    double* wsd = (double*)(wsf + offf);
    double* partial = wsd;          // up to 256 blocks x (2*32+1) doubles
    double* params = wsd + 16640;
    u8* wsm = (u8*)(wsd + 16640 + 128);
    size_t offm = 0;
    auto allocm = [&](size_t n) { u8* p = wsm + offm; offm += n; return p; };
    u8* m32 = allocm(4194304);
    u8* m16 = allocm(524288);
    u8* m8 = allocm(65536);
    u8* m4 = allocm(8192);
    u8* mD8 = allocm(65536);
    u8* mD16 = allocm(524288);
    u8* mD32 = allocm(4194304);
    // active-group list: aliases S2 (4 MB; lifetimes verified disjoint:
    //  glist used [start..convbn4c], slist/dlist used in decoder stage 2;
    //  S2 live only [enc stage2 .. dec stage0])
    int* list = (int*)S2;
    int* gcnt = (int*)(wsm + offm);   // 4 bytes past the mask region

    const int N32 = 128 * 32768;
    const int N16 = 128 * 4096;
    const int N8 = 128 * 512;
    const int N4 = 128 * 64;
    const int NG32 = N32 / 4;
    auto gs = [](int n) { return dim3((n + 255) / 256); };
    auto rbn = [](int n) { int bl = (n + 255) / 256; return bl > 256 ? 256 : bl; };
    dim3 blk(256);

    // masks
    mask_init_k<<<gs(N32), blk, 0, stream>>>(mraw, m32, N32);
    pool_k<16><<<gs(N16), blk, 0, stream>>>(m32, m16);
    pool_k<8><<<gs(N8), blk, 0, stream>>>(m16, m8);
    pool_k<4><<<gs(N4), blk, 0, stream>>>(m8, m4);

    // ---- encoder stage 0 @32^3, list-driven on m32 groups ----
    hipMemsetAsync(gcnt, 0, 4, stream);
    build_glist_k<<<gs(NG32), blk, 0, stream>>>(m32, list, gcnt);
    prep4c_k<<<gs(NG32), blk, 0, stream>>>(vox, m32, wp, R1, list, gcnt);
    int nb0 = rbn(N32);
    bn_reduce_k<4><<<dim3(nb0), blk, 0, stream>>>(R1, m32, N32, partial);
    bn_final_k<4><<<1, 64, 0, stream>>>(partial, nb0, g_e0, b_e0, params);
    hipMemsetAsync(R2, 0, (size_t)N32 * 4 * sizeof(float), stream);   // down_k reads unmasked
    convbn4c_k<<<gs(NG32), blk, 0, stream>>>(R1, ws_e0, m32, params, R2, list, gcnt);
    down_k<4, 8, 16><<<gs(N16), blk, 0, stream>>>(R2, wd_e0, m16, R1);

    // ---- encoder stage 1 @16^3 ----
    int nb1 = rbn(N16);
    bn_reduce_k<8><<<dim3(nb1), blk, 0, stream>>>(R1, m16, N16, partial);
    bn_final_k<8><<<1, 64, 0, stream>>>(partial, nb1, g_e1, b_e1, params);
    convbn_k<8, 8, 16><<<gs(N16), blk, 0, stream>>>(R1, ws_e1, m16, params, R2);
    down_k<8, 16, 8><<<gs(N8), blk, 0, stream>>>(R2, wd_e1, m8, S1);

    // ---- encoder stage 2 @8^3 ----
    int nb2 = rbn(N8);
    bn_reduce_k<16><<<dim3(nb2), blk, 0, stream>>>(S1, m8, N8, partial);
    bn_final_k<16><<<1, 64, 0, stream>>>(partial, nb2, g_e2, b_e2, params);
    convbn_k<16, 16, 8><<<gs(N8), blk, 0, stream>>>(S1, ws_e2, m8, params, S2);
    down_k<16, 32, 4><<<gs(N4), blk, 0, stream>>>(S2, wd_e2, m4, T);

    // ---- hidden ----
    hidden_k<<<gs(128 * 2048), blk, 0, stream>>>(T, out);

    // ---- decoder stage 0 (32->16, 4^3 -> 8^3), band gate delta=4e-7 ----
    int nb3 = rbn(N4);
    bn_reduce_k<32><<<dim3(nb3), blk, 0, stream>>>(T, m4, N4, partial);
    bn_final_k<32><<<1, 64, 0, stream>>>(partial, nb3, g_d0, b_d0, params);
    upbn_k<32, 16, 4><<<gs(N8), blk, 0, stream>>>(T, wu_d0, m4, params, S1);
    conv3s_k<16, 16, 8><<<gs(N8), blk, 0, stream>>>(S1, ws3_d0, m4, mD8, S2, 4e-7);
    conv_k<4, 16, 16, 8><<<gs(N8), blk, 0, stream>>>(S2, ws4_d0, mD8, S1);

    // ---- decoder stage 1 (16->8, 8^3 -> 16^3), band gate delta=4e-7 ----
    int nb4 = rbn(N8);
    bn_reduce_k<16><<<dim3(nb4), blk, 0, stream>>>(S1, mD8, N8, partial);
    bn_final_k<16><<<1, 64, 0, stream>>>(partial, nb4, g_d1, b_d1, params);
    upbn_k<16, 8, 8><<<gs(N16), blk, 0, stream>>>(S1, wu_d1, mD8, params, R1);
    conv3s_k<8, 8, 16><<<gs(N16), blk, 0, stream>>>(R1, ws3_d1, mD8, mD16, R2, 4e-7);
    conv_k<4, 8, 8, 16><<<gs(N16), blk, 0, stream>>>(R2, ws4_d1, mD16, R1);

    // ---- decoder stage 2 (8->4, 16^3 -> 32^3), exact gate, list-driven ----
    int nb5 = rbn(N16);
    bn_reduce_k<8><<<dim3(nb5), blk, 0, stream>>>(R1, mD16, N16, partial);
    bn_final_k<8><<<1, 64, 0, stream>>>(partial, nb5, g_d2, b_d2, params);
    upbn_k<8, 4, 16><<<gs(N32), blk, 0, stream>>>(R1, wu_d2, mD16, params, R2);
    // conv3s4: gate = mD16 pairs; pre-zero its outputs (R1 + mD32)
    hipMemsetAsync(R1, 0, (size_t)N32 * 4 * sizeof(float), stream);
    hipMemsetAsync(mD32, 0, (size_t)N32, stream);
    hipMemsetAsync(gcnt, 0, 4, stream);
    build_slist_k<<<gs(NG32), blk, 0, stream>>>(mD16, list, gcnt);
    conv3s4c_k<<<gs(NG32), blk, 0, stream>>>(R2, ws3_d2, mD16, mD32, R1, 0.0, list, gcnt);
    // conv4x4 + outconv: gate = mD32 groups; pre-zero their outputs
    hipMemsetAsync(R2, 0, (size_t)N32 * 4 * sizeof(float), stream);
    hipMemsetAsync(gcnt, 0, 4, stream);
    build_glist_k<<<gs(NG32), blk, 0, stream>>>(mD32, list, gcnt);
    conv4x4c_k<<<gs(NG32), blk, 0, stream>>>(R1, ws4_d2, mD32, R2, list, gcnt);
    hipMemsetAsync(out + 262144, 0, (size_t)N32 * sizeof(float), stream);
    outconv4c_k<<<gs(NG32), blk, 0, stream>>>(R2, wo, mD32, out + 262144, list, gcnt);
}

// Round 2
// 1685.437 us; speedup vs baseline: 1.3220x; 1.3220x over previous
//
#include <hip/hip_runtime.h>

using u8 = unsigned char;

// ---------------- mask init: m = (maskraw == 0) ----------------
__global__ void mask_init_k(const int* __restrict__ mr, u8* __restrict__ m, int N) {
    int i = blockIdx.x * blockDim.x + threadIdx.x;
    if (i < N) m[i] = (mr[i] == 0) ? 1 : 0;
}

// ---------------- mask pool 2x2x2 (logical OR), full batch ----------------
template <int SO>
__global__ void pool_k(const u8* __restrict__ mi, u8* __restrict__ mo) {
    const int N = 128 * SO * SO * SO;
    constexpr int SI = 2 * SO;
    int v = blockIdx.x * blockDim.x + threadIdx.x;
    if (v >= N) return;
    int t = v;
    int x = t % SO; t /= SO;
    int y = t % SO; t /= SO;
    int z = t % SO;
    int n = t / SO;
    u8 m = 0;
    for (int kd = 0; kd < 2; kd++)
        for (int kh = 0; kh < 2; kh++)
            for (int kw = 0; kw < 2; kw++)
                m |= mi[((n * SI + 2 * z + kd) * SI + 2 * y + kh) * SI + 2 * x + kw];
    mo[v] = m;
}

// ================= ordered active-group list (32^3, groups of 4 consecutive x) =================
// group g: xb=(g&7)*4, y=(g>>3)&31, z=(g>>8)&31, n=g>>13, vbase=((g>>3)<<5)+xb
// Built via deterministic scan (no atomics): count -> exclusive scan -> ballot-rank fill.
// List is in ascending g order, preserving x/y spatial locality within waves.

// MODE 0: group active iff any of its 4 mask bytes set (mask buffer 4-byte aligned)
// MODE 1: group active iff either of its two parent (16^3) mask bytes set (conv3s4 gate)
template <int MODE>
__device__ inline bool grp_pred(const u8* __restrict__ m, int g) {
    if (MODE == 0) {
        return *(const unsigned*)(m + ((size_t)g << 2)) != 0u;
    } else {
        int xb = (g & 7) << 2;
        int y = (g >> 3) & 31;
        int z = (g >> 8) & 31;
        int n = g >> 13;
        int pbase = ((n * 16 + (z >> 1)) * 16 + (y >> 1)) * 16 + (xb >> 1);
        return *(const unsigned short*)(m + pbase) != 0;
    }
}

template <int MODE>
__global__ void glist_count_k(const u8* __restrict__ m, int* __restrict__ bcnt) {
    int g = blockIdx.x * 256 + threadIdx.x;
    bool act = grp_pred<MODE>(m, g);
    unsigned long long bal = __ballot(act);
    __shared__ int wsum[4];
    int lane = threadIdx.x & 63, wave = threadIdx.x >> 6;
    if (lane == 0) wsum[wave] = __popcll(bal);
    __syncthreads();
    if (threadIdx.x == 0) bcnt[blockIdx.x] = wsum[0] + wsum[1] + wsum[2] + wsum[3];
}

// exclusive scan over exactly 4096 block counts; writes offsets + grand total
__global__ void scan4096_k(const int* __restrict__ bcnt, int* __restrict__ boff,
                           int* __restrict__ total) {
    __shared__ int tsum[256];
    __shared__ int texc[256];
    int t = threadIdx.x;
    int local[16];
    int s = 0;
#pragma unroll
    for (int k = 0; k < 16; k++) { local[k] = bcnt[t * 16 + k]; s += local[k]; }
    tsum[t] = s;
    __syncthreads();
    if (t == 0) {
        int run = 0;
        for (int i = 0; i < 256; i++) { texc[i] = run; run += tsum[i]; }
        *total = run;
    }
    __syncthreads();
    int run = texc[t];
#pragma unroll
    for (int k = 0; k < 16; k++) { boff[t * 16 + k] = run; run += local[k]; }
}

template <int MODE>
__global__ void glist_fill_k(const u8* __restrict__ m, const int* __restrict__ boff,
                             int* __restrict__ list) {
    int g = blockIdx.x * 256 + threadIdx.x;
    bool act = grp_pred<MODE>(m, g);
    unsigned long long bal = __ballot(act);
    int lane = threadIdx.x & 63, wave = threadIdx.x >> 6;
    __shared__ int woff[4];
    if (lane == 0) woff[wave] = __popcll(bal);
    __syncthreads();
    if (threadIdx.x == 0) {
        int r = boff[blockIdx.x];
        for (int wv = 0; wv < 4; wv++) { int c = woff[wv]; woff[wv] = r; r += c; }
    }
    __syncthreads();
    if (act) {
        int rank = __popcll(bal & ((1ULL << lane) - 1ULL));
        list[woff[wave] + rank] = g;
    }
}

// ================= 32^3 XPT=4 list-driven kernels =================

// ---------------- prepare conv 1->4, k=3, masked input+output (no prezero needed:
// consumers bn_reduce/convbn4c are mask-checked) ----------------
__global__ void prep4c_k(const float* __restrict__ vox, const u8* __restrict__ m,
                         const float* __restrict__ wp, float* __restrict__ out,
                         const int* __restrict__ list, const int* __restrict__ cnt) {
    int i = blockIdx.x * blockDim.x + threadIdx.x;
    if (i >= *cnt) return;
    int g = list[i];
    int xb = (g & 7) << 2;
    int y = (g >> 3) & 31;
    int z = (g >> 8) & 31;
    int n = g >> 13;
    int vbase = ((g >> 3) << 5) + xb;
    u8 om[4];
#pragma unroll
    for (int j = 0; j < 4; j++) om[j] = m[vbase + j];
    float acc[4][4];
#pragma unroll
    for (int j = 0; j < 4; j++)
#pragma unroll
        for (int co = 0; co < 4; co++) acc[j][co] = 0.f;
    for (int kd = 0; kd < 3; kd++) {
        int zz = z + kd - 1; if ((unsigned)zz >= 32u) continue;
        for (int kh = 0; kh < 3; kh++) {
            int yy = y + kh - 1; if ((unsigned)yy >= 32u) continue;
            int base = ((n * 32 + zz) * 32 + yy) * 32;
            float col[6];
#pragma unroll
            for (int c = 0; c < 6; c++) {
                int xx = xb - 1 + c;
                col[c] = ((unsigned)xx < 32u && m[base + xx]) ? vox[base + xx] : 0.f;
            }
            const float* wrow = wp + ((kd * 3 + kh) * 3) * 4;
#pragma unroll
            for (int kw = 0; kw < 3; kw++) {
                const float* wt = wrow + kw * 4;
#pragma unroll
                for (int j = 0; j < 4; j++) {
                    float xv = col[j + kw];
#pragma unroll
                    for (int co = 0; co < 4; co++) acc[j][co] += xv * wt[co];
                }
            }
        }
    }
#pragma unroll
    for (int j = 0; j < 4; j++)
#pragma unroll
        for (int co = 0; co < 4; co++)
            out[(size_t)(vbase + j) * 4 + co] = om[j] ? acc[j][co] : 0.f;
}

// ---------------- conv k=3, 4->4, BN(affine+ReLU+mask) on load, list-driven
// (output pre-zeroed: down_k reads unmasked) ----------------
__global__ void convbn4c_k(const float* __restrict__ in, const float* __restrict__ w,
                           const u8* __restrict__ mask, const double* __restrict__ params,
                           float* __restrict__ out,
                           const int* __restrict__ list, const int* __restrict__ cnt) {
    int i = blockIdx.x * blockDim.x + threadIdx.x;
    if (i >= *cnt) return;
    int g = list[i];
    int xb = (g & 7) << 2;
    int y = (g >> 3) & 31;
    int z = (g >> 8) & 31;
    int n = g >> 13;
    int vbase = ((g >> 3) << 5) + xb;
    u8 om[4];
#pragma unroll
    for (int j = 0; j < 4; j++) om[j] = mask[vbase + j];
    float sc[4], sh[4];
#pragma unroll
    for (int c = 0; c < 4; c++) { sc[c] = (float)params[c]; sh[c] = (float)params[4 + c]; }
    float acc[4][4];
#pragma unroll
    for (int j = 0; j < 4; j++)
#pragma unroll
        for (int co = 0; co < 4; co++) acc[j][co] = 0.f;
    for (int kd = 0; kd < 3; kd++) {
        int zz = z + kd - 1; if ((unsigned)zz >= 32u) continue;
        for (int kh = 0; kh < 3; kh++) {
            int yy = y + kh - 1; if ((unsigned)yy >= 32u) continue;
            int base = ((n * 32 + zz) * 32 + yy) * 32;
            float col[6][4];
#pragma unroll
            for (int c = 0; c < 6; c++) {
                int xx = xb - 1 + c;
                bool valid = ((unsigned)xx < 32u) && mask[base + xx];
                const float* ip = in + (size_t)(base + xx) * 4;
#pragma unroll
                for (int ci = 0; ci < 4; ci++)
                    col[c][ci] = valid ? fmaxf(ip[ci] * sc[ci] + sh[ci], 0.f) : 0.f;
            }
            const float* wrow = w + ((kd * 3 + kh) * 3) * 16;
#pragma unroll
            for (int kw = 0; kw < 3; kw++) {
                const float* wt = wrow + kw * 16;
#pragma unroll
                for (int j = 0; j < 4; j++) {
#pragma unroll
                    for (int ci = 0; ci < 4; ci++) {
                        float xv = col[j + kw][ci];
#pragma unroll
                        for (int co = 0; co < 4; co++) acc[j][co] += xv * wt[ci * 4 + co];
                    }
                }
            }
        }
    }
#pragma unroll
    for (int j = 0; j < 4; j++)
#pragma unroll
        for (int co = 0; co < 4; co++)
            out[(size_t)(vbase + j) * 4 + co] = om[j] ? acc[j][co] : 0.f;
}

// ---------------- plain conv 4->4, k=4 pad(1,2), list-driven (output pre-zeroed) ----------------
__global__ void conv4x4c_k(const float* __restrict__ in, const float* __restrict__ w,
                           const u8* __restrict__ outmask, float* __restrict__ out,
                           const int* __restrict__ list, const int* __restrict__ cnt) {
    constexpr int K = 4;
    constexpr int PLO = (K - 1) / 2;
    constexpr int NC = K + 3;
    int i = blockIdx.x * blockDim.x + threadIdx.x;
    if (i >= *cnt) return;
    int g = list[i];
    int xb = (g & 7) << 2;
    int y = (g >> 3) & 31;
    int z = (g >> 8) & 31;
    int n = g >> 13;
    int vbase = ((g >> 3) << 5) + xb;
    u8 om[4];
#pragma unroll
    for (int j = 0; j < 4; j++) om[j] = outmask[vbase + j];
    float acc[4][4];
#pragma unroll
    for (int j = 0; j < 4; j++)
#pragma unroll
        for (int co = 0; co < 4; co++) acc[j][co] = 0.f;
    for (int kd = 0; kd < K; kd++) {
        int zz = z + kd - PLO; if ((unsigned)zz >= 32u) continue;
        for (int kh = 0; kh < K; kh++) {
            int yy = y + kh - PLO; if ((unsigned)yy >= 32u) continue;
            int base = ((n * 32 + zz) * 32 + yy) * 32;
            float col[NC][4];
#pragma unroll
            for (int c = 0; c < NC; c++) {
                int xx = xb - PLO + c;
                bool valid = ((unsigned)xx < 32u);
                const float* ip = in + (size_t)(base + xx) * 4;
#pragma unroll
                for (int ci = 0; ci < 4; ci++) col[c][ci] = valid ? ip[ci] : 0.f;
            }
            const float* wrow = w + ((kd * K + kh) * K) * 16;
#pragma unroll
            for (int kw = 0; kw < K; kw++) {
                const float* wt = wrow + kw * 16;
#pragma unroll
                for (int j = 0; j < 4; j++) {
#pragma unroll
                    for (int ci = 0; ci < 4; ci++) {
                        float xv = col[j + kw][ci];
#pragma unroll
                        for (int co = 0; co < 4; co++) acc[j][co] += xv * wt[ci * 4 + co];
                    }
                }
            }
        }
    }
#pragma unroll
    for (int j = 0; j < 4; j++)
#pragma unroll
        for (int co = 0; co < 4; co++)
            out[(size_t)(vbase + j) * 4 + co] = om[j] ? acc[j][co] : 0.f;
}

// ---------------- conv k=3 4->4 + fused sparsify (fp64 gate), list-driven
// (out + nmask pre-zeroed) ----------------
__global__ void conv3s4c_k(const float* __restrict__ in, const float* __restrict__ w,
                           const u8* __restrict__ pmask, u8* __restrict__ nmask,
                           float* __restrict__ out, double delta,
                           const int* __restrict__ list, const int* __restrict__ cnt) {
    int i = blockIdx.x * blockDim.x + threadIdx.x;
    if (i >= *cnt) return;
    int g = list[i];
    int xb = (g & 7) << 2;
    int y = (g >> 3) & 31;
    int z = (g >> 8) & 31;
    int n = g >> 13;
    int vbase = ((g >> 3) << 5) + xb;
    int pbase = ((n * 16 + (z >> 1)) * 16 + (y >> 1)) * 16 + (xb >> 1);
    u8 pm[4];
    pm[0] = pm[1] = pmask[pbase];
    pm[2] = pm[3] = pmask[pbase + 1];
    double acc0[4], asum[4];
    float accf[4][4];
#pragma unroll
    for (int j = 0; j < 4; j++) {
        acc0[j] = 0.0; asum[j] = 0.0;
#pragma unroll
        for (int co = 0; co < 4; co++) accf[j][co] = 0.f;
    }
    for (int kd = 0; kd < 3; kd++) {
        int zz = z + kd - 1; if ((unsigned)zz >= 32u) continue;
        for (int kh = 0; kh < 3; kh++) {
            int yy = y + kh - 1; if ((unsigned)yy >= 32u) continue;
            int base = ((n * 32 + zz) * 32 + yy) * 32;
            float col[6][4];
#pragma unroll
            for (int c = 0; c < 6; c++) {
                int xx = xb - 1 + c;
                bool valid = ((unsigned)xx < 32u);
                const float* ip = in + (size_t)(base + xx) * 4;
#pragma unroll
                for (int ci = 0; ci < 4; ci++) col[c][ci] = valid ? ip[ci] : 0.f;
            }
            const float* wrow = w + ((kd * 3 + kh) * 3) * 16;
#pragma unroll
            for (int kw = 0; kw < 3; kw++) {
                const float* wt = wrow + kw * 16;
#pragma unroll
                for (int j = 0; j < 4; j++) {
#pragma unroll
                    for (int ci = 0; ci < 4; ci++) {
                        float xv = col[j + kw][ci];
                        double term = (double)xv * (double)wt[ci * 4 + 0];
                        acc0[j] += term;
                        asum[j] += fabs(term);
#pragma unroll
                        for (int co = 1; co < 4; co++) accf[j][co] += xv * wt[ci * 4 + co];
                    }
                }
            }
        }
    }
#pragma unroll
    for (int j = 0; j < 4; j++) {
        u8 nm = (pm[j] && (acc0[j] > -delta * asum[j])) ? 1 : 0;
        nmask[vbase + j] = nm;
        out[(size_t)(vbase + j) * 4 + 0] = nm ? (float)acc0[j] : 0.f;
#pragma unroll
        for (int co = 1; co < 4; co++) out[(size_t)(vbase + j) * 4 + co] = nm ? accf[j][co] : 0.f;
    }
}

// ---------------- final output conv k=3, 4->1, list-driven (output pre-zeroed) ----------------
__global__ void outconv4c_k(const float* __restrict__ in, const float* __restrict__ w,
                            const u8* __restrict__ mask, float* __restrict__ out,
                            const int* __restrict__ list, const int* __restrict__ cnt) {
    int i = blockIdx.x * blockDim.x + threadIdx.x;
    if (i >= *cnt) return;
    int g = list[i];
    int xb = (g & 7) << 2;
    int y = (g >> 3) & 31;
    int z = (g >> 8) & 31;
    int n = g >> 13;
    int vbase = ((g >> 3) << 5) + xb;
    u8 om[4];
#pragma unroll
    for (int j = 0; j < 4; j++) om[j] = mask[vbase + j];
    float acc[4] = {0.f, 0.f, 0.f, 0.f};
    for (int kd = 0; kd < 3; kd++) {
        int zz = z + kd - 1; if ((unsigned)zz >= 32u) continue;
        for (int kh = 0; kh < 3; kh++) {
            int yy = y + kh - 1; if ((unsigned)yy >= 32u) continue;
            int base = ((n * 32 + zz) * 32 + yy) * 32;
            float col[6][4];
#pragma unroll
            for (int c = 0; c < 6; c++) {
                int xx = xb - 1 + c;
                bool valid = ((unsigned)xx < 32u);
                const float* ip = in + (size_t)(base + xx) * 4;
#pragma unroll
                for (int ci = 0; ci < 4; ci++) col[c][ci] = valid ? ip[ci] : 0.f;
            }
            const float* wrow = w + ((kd * 3 + kh) * 3) * 4;
#pragma unroll
            for (int kw = 0; kw < 3; kw++) {
                const float* wt = wrow + kw * 4;
#pragma unroll
                for (int j = 0; j < 4; j++) {
#pragma unroll
                    for (int ci = 0; ci < 4; ci++) acc[j] += col[j + kw][ci] * wt[ci];
                }
            }
        }
    }
#pragma unroll
    for (int j = 0; j < 4; j++) out[vbase + j] = om[j] ? acc[j] : 0.f;
}

// ================= generic kernels for 16^3 / 8^3 stages (unchanged) =================

template <int K, int CIN, int COUT, int S>
__global__ void conv_k(const float* __restrict__ in, const float* __restrict__ w,
                       const u8* __restrict__ outmask, float* __restrict__ out) {
    const int N = 128 * S * S * S;
    int v = blockIdx.x * blockDim.x + threadIdx.x;
    if (v >= N) return;
    if (!outmask[v]) {
#pragma unroll
        for (int co = 0; co < COUT; co++) out[(size_t)v * COUT + co] = 0.f;
        return;
    }
    int t = v;
    int x = t % S; t /= S;
    int y = t % S; t /= S;
    int z = t % S;
    int n = t / S;
    float acc[COUT];
#pragma unroll
    for (int co = 0; co < COUT; co++) acc[co] = 0.f;
    constexpr int PLO = (K - 1) / 2;
    for (int kd = 0; kd < K; kd++) {
        int zz = z + kd - PLO; if ((unsigned)zz >= (unsigned)S) continue;
        for (int kh = 0; kh < K; kh++) {
            int yy = y + kh - PLO; if ((unsigned)yy >= (unsigned)S) continue;
            for (int kw = 0; kw < K; kw++) {
                int xx = x + kw - PLO; if ((unsigned)xx >= (unsigned)S) continue;
                int sv = ((n * S + zz) * S + yy) * S + xx;
                const float* ip = in + (size_t)sv * CIN;
                const float* wpk = w + ((kd * K + kh) * K + kw) * CIN * COUT;
#pragma unroll
                for (int ci = 0; ci < CIN; ci++) {
                    float xv = ip[ci];
#pragma unroll
                    for (int co = 0; co < COUT; co++) acc[co] += xv * wpk[ci * COUT + co];
                }
            }
        }
    }
#pragma unroll
    for (int co = 0; co < COUT; co++) out[(size_t)v * COUT + co] = acc[co];
}

template <int CIN, int COUT, int S>
__global__ void convbn_k(const float* __restrict__ in, const float* __restrict__ w,
                         const u8* __restrict__ mask, const double* __restrict__ params,
                         float* __restrict__ out) {
    const int N = 128 * S * S * S;
    int v = blockIdx.x * blockDim.x + threadIdx.x;
    if (v >= N) return;
    if (!mask[v]) {
#pragma unroll
        for (int co = 0; co < COUT; co++) out[(size_t)v * COUT + co] = 0.f;
        return;
    }
    int t = v;
    int x = t % S; t /= S;
    int y = t % S; t /= S;
    int z = t % S;
    int n = t / S;
    float sc[CIN], sh[CIN];
#pragma unroll
    for (int c = 0; c < CIN; c++) { sc[c] = (float)params[c]; sh[c] = (float)params[CIN + c]; }
    float acc[COUT];
#pragma unroll
    for (int co = 0; co < COUT; co++) acc[co] = 0.f;
    for (int kd = 0; kd < 3; kd++) {
        int zz = z + kd - 1; if ((unsigned)zz >= (unsigned)S) continue;
        for (int kh = 0; kh < 3; kh++) {
            int yy = y + kh - 1; if ((unsigned)yy >= (unsigned)S) continue;
            for (int kw = 0; kw < 3; kw++) {
                int xx = x + kw - 1; if ((unsigned)xx >= (unsigned)S) continue;
                int sv = ((n * S + zz) * S + yy) * S + xx;
                if (!mask[sv]) continue;
                const float* ip = in + (size_t)sv * CIN;
                const float* wpk = w + ((kd * 3 + kh) * 3 + kw) * CIN * COUT;
#pragma unroll
                for (int ci = 0; ci < CIN; ci++) {
                    float yv = fmaxf(ip[ci] * sc[ci] + sh[ci], 0.f);
#pragma unroll
                    for (int co = 0; co < COUT; co++) acc[co] += yv * wpk[ci * COUT + co];
                }
            }
        }
    }
#pragma unroll
    for (int co = 0; co < COUT; co++) out[(size_t)v * COUT + co] = acc[co];
}

template <int CIN, int COUT, int S>
__global__ void conv3s_k(const float* __restrict__ in, const float* __restrict__ w,
                         const u8* __restrict__ pmask, u8* __restrict__ nmask,
                         float* __restrict__ out, double delta) {
    const int N = 128 * S * S * S;
    constexpr int SP = S / 2;
    int v = blockIdx.x * blockDim.x + threadIdx.x;
    if (v >= N) return;
    int t = v;
    int x = t % S; t /= S;
    int y = t % S; t /= S;
    int z = t % S;
    int n = t / S;
    int pidx = ((n * SP + (z >> 1)) * SP + (y >> 1)) * SP + (x >> 1);
    if (!pmask[pidx]) {
        nmask[v] = 0;
#pragma unroll
        for (int co = 0; co < COUT; co++) out[(size_t)v * COUT + co] = 0.f;
        return;
    }
    double acc0 = 0.0, asum = 0.0;
    float acc[COUT];
#pragma unroll
    for (int co = 0; co < COUT; co++) acc[co] = 0.f;
    for (int kd = 0; kd < 3; kd++) {
        int zz = z + kd - 1; if ((unsigned)zz >= (unsigned)S) continue;
        for (int kh = 0; kh < 3; kh++) {
            int yy = y + kh - 1; if ((unsigned)yy >= (unsigned)S) continue;
            for (int kw = 0; kw < 3; kw++) {
                int xx = x + kw - 1; if ((unsigned)xx >= (unsigned)S) continue;
                int sv = ((n * S + zz) * S + yy) * S + xx;
                const float* ip = in + (size_t)sv * CIN;
                const float* wpk = w + ((kd * 3 + kh) * 3 + kw) * CIN * COUT;
#pragma unroll
                for (int ci = 0; ci < CIN; ci++) {
                    float xv = ip[ci];
                    double term = (double)xv * (double)wpk[ci * COUT + 0];
                    acc0 += term;
                    asum += fabs(term);
#pragma unroll
                    for (int co = 1; co < COUT; co++) acc[co] += xv * wpk[ci * COUT + co];
                }
            }
        }
    }
    u8 nm = (acc0 > -delta * asum) ? 1 : 0;
    nmask[v] = nm;
    out[(size_t)v * COUT + 0] = nm ? (float)acc0 : 0.f;
#pragma unroll
    for (int co = 1; co < COUT; co++) out[(size_t)v * COUT + co] = nm ? acc[co] : 0.f;
}

template <int CIN, int COUT, int SO>
__global__ void down_k(const float* __restrict__ in, const float* __restrict__ w,
                       const u8* __restrict__ outmask, float* __restrict__ out) {
    const int N = 128 * SO * SO * SO;
    constexpr int SI = 2 * SO;
    int v = blockIdx.x * blockDim.x + threadIdx.x;
    if (v >= N) return;
    if (!outmask[v]) {
#pragma unroll
        for (int co = 0; co < COUT; co++) out[(size_t)v * COUT + co] = 0.f;
        return;
    }
    int t = v;
    int x = t % SO; t /= SO;
    int y = t % SO; t /= SO;
    int z = t % SO;
    int n = t / SO;
    float acc[COUT];
#pragma unroll
    for (int co = 0; co < COUT; co++) acc[co] = 0.f;
    for (int kd = 0; kd < 2; kd++)
        for (int kh = 0; kh < 2; kh++)
            for (int kw = 0; kw < 2; kw++) {
                int sv = ((n * SI + 2 * z + kd) * SI + 2 * y + kh) * SI + 2 * x + kw;
                const float* ip = in + (size_t)sv * CIN;
                const float* wpk = w + ((kd * 2 + kh) * 2 + kw) * CIN * COUT;
#pragma unroll
                for (int ci = 0; ci < CIN; ci++) {
                    float xv = ip[ci];
#pragma unroll
                    for (int co = 0; co < COUT; co++) acc[co] += xv * wpk[ci * COUT + co];
                }
            }
#pragma unroll
    for (int co = 0; co < COUT; co++) out[(size_t)v * COUT + co] = acc[co];
}

template <int CIN, int COUT, int SI>
__global__ void upbn_k(const float* __restrict__ in, const float* __restrict__ w,
                       const u8* __restrict__ inmask, const double* __restrict__ params,
                       float* __restrict__ out) {
    constexpr int SO = 2 * SI;
    const int N = 128 * SO * SO * SO;
    int v = blockIdx.x * blockDim.x + threadIdx.x;
    if (v >= N) return;
    int t = v;
    int x = t % SO; t /= SO;
    int y = t % SO; t /= SO;
    int z = t % SO;
    int n = t / SO;
    int sv = ((n * SI + (z >> 1)) * SI + (y >> 1)) * SI + (x >> 1);
    if (!inmask[sv]) {
#pragma unroll
        for (int co = 0; co < COUT; co++) out[(size_t)v * COUT + co] = 0.f;
        return;
    }
    int tap = ((1 - (z & 1)) * 2 + (1 - (y & 1))) * 2 + (1 - (x & 1));
    const float* wpk = w + tap * CIN * COUT;
    const float* ip = in + (size_t)sv * CIN;
    float acc[COUT];
#pragma unroll
    for (int co = 0; co < COUT; co++) acc[co] = 0.f;
#pragma unroll
    for (int ci = 0; ci < CIN; ci++) {
        float yv = fmaxf(ip[ci] * (float)params[ci] + (float)params[CIN + ci], 0.f);
#pragma unroll
        for (int co = 0; co < COUT; co++) acc[co] += yv * wpk[ci * COUT + co];
    }
#pragma unroll
    for (int co = 0; co < COUT; co++) out[(size_t)v * COUT + co] = acc[co];
}

// ---------------- BN masked reduce, DETERMINISTIC two-pass: per-block partials ----------------
template <int C>
__global__ void bn_reduce_k(const float* __restrict__ x, const u8* __restrict__ m, int N,
                            double* __restrict__ partial) {
    double cnt = 0.0, sx[C], s2[C];
#pragma unroll
    for (int c = 0; c < C; c++) { sx[c] = 0.0; s2[c] = 0.0; }
    int stride = gridDim.x * blockDim.x;
    for (int v = blockIdx.x * blockDim.x + threadIdx.x; v < N; v += stride) {
        if (!m[v]) continue;
        cnt += 1.0;
#pragma unroll
        for (int c = 0; c < C; c++) {
            double xv = (double)x[(size_t)v * C + c];
            sx[c] += xv;
            s2[c] += xv * xv;
        }
    }
#pragma unroll
    for (int off = 32; off > 0; off >>= 1) {
        cnt += __shfl_down(cnt, off, 64);
#pragma unroll
        for (int c = 0; c < C; c++) {
            sx[c] += __shfl_down(sx[c], off, 64);
            s2[c] += __shfl_down(s2[c], off, 64);
        }
    }
    __shared__ double sbuf[4][2 * C + 1];
    int wave = threadIdx.x >> 6;
    if ((threadIdx.x & 63) == 0) {
        sbuf[wave][0] = cnt;
#pragma unroll
        for (int c = 0; c < C; c++) {
            sbuf[wave][1 + c] = sx[c];
            sbuf[wave][1 + C + c] = s2[c];
        }
    }
    __syncthreads();
    if (threadIdx.x == 0) {
        double* p = partial + (size_t)blockIdx.x * (2 * C + 1);
        double tcnt = 0.0;
        for (int wv = 0; wv < 4; wv++) tcnt += sbuf[wv][0];
        p[0] = tcnt;
#pragma unroll
        for (int c = 0; c < C; c++) {
            double a = 0.0, b = 0.0;
            for (int wv = 0; wv < 4; wv++) { a += sbuf[wv][1 + c]; b += sbuf[wv][1 + C + c]; }
            p[1 + c] = a;
            p[1 + C + c] = b;
        }
    }
}

// ---------------- BN finalize: fixed-order sum of block partials ----------------
template <int C>
__global__ void bn_final_k(const double* __restrict__ partial, int nblocks,
                           const float* __restrict__ g, const float* __restrict__ b,
                           double* __restrict__ params) {
    int c = threadIdx.x;
    if (c >= C) return;
    double cnt = 0.0, sx = 0.0, s2 = 0.0;
    for (int bk = 0; bk < nblocks; bk++) {
        const double* p = partial + (size_t)bk * (2 * C + 1);
        cnt += p[0];
        sx += p[1 + c];
        s2 += p[1 + C + c];
    }
    if (cnt < 1.0) cnt = 1.0;
    double mean = sx / cnt;
    double var = s2 / cnt - mean * mean;
    double sc = (double)g[c] / sqrt(var + 1e-4);
    params[c] = sc;
    params[C + c] = (double)b[c] - mean * sc;
}

// ---------------- hidden: NDHWC (4^3, 32ch) -> NCDHW flat ----------------
__global__ void hidden_k(const float* __restrict__ x, float* __restrict__ out) {
    int i = blockIdx.x * blockDim.x + threadIdx.x;
    if (i >= 128 * 2048) return;
    int b = i >> 11;
    int r = i & 2047;
    int c = r >> 6;
    int s = r & 63;
    int d = s >> 4;
    int h = (s >> 2) & 3;
    int w = s & 3;
    out[i] = x[((((b * 4 + d) * 4 + h) * 4 + w) << 5) + c];
}

extern "C" void kernel_launch(void* const* d_in, const int* in_sizes, int n_in,
                              void* d_out, int out_size, void* d_ws, size_t ws_size,
                              hipStream_t stream) {
    const float* vox = (const float*)d_in[0];
    const int* mraw = (const int*)d_in[1];
    const float* wp = (const float*)d_in[2];
    const float* g_e0 = (const float*)d_in[3];
    const float* b_e0 = (const float*)d_in[4];
    const float* ws_e0 = (const float*)d_in[5];
    const float* wd_e0 = (const float*)d_in[6];
    const float* g_e1 = (const float*)d_in[7];
    const float* b_e1 = (const float*)d_in[8];
    const float* ws_e1 = (const float*)d_in[9];
    const float* wd_e1 = (const float*)d_in[10];
    const float* g_e2 = (const float*)d_in[11];
    const float* b_e2 = (const float*)d_in[12];
    const float* ws_e2 = (const float*)d_in[13];
    const float* wd_e2 = (const float*)d_in[14];
    const float* g_d0 = (const float*)d_in[15];
    const float* b_d0 = (const float*)d_in[16];
    const float* wu_d0 = (const float*)d_in[17];
    const float* ws3_d0 = (const float*)d_in[18];
    const float* ws4_d0 = (const float*)d_in[19];
    const float* g_d1 = (const float*)d_in[20];
    const float* b_d1 = (const float*)d_in[21];
    const float* wu_d1 = (const float*)d_in[22];
    const float* ws3_d1 = (const float*)d_in[23];
    const float* ws4_d1 = (const float*)d_in[24];
    const float* g_d2 = (const float*)d_in[25];
    const float* b_d2 = (const float*)d_in[26];
    const float* wu_d2 = (const float*)d_in[27];
    const float* ws3_d2 = (const float*)d_in[28];
    const float* ws4_d2 = (const float*)d_in[29];
    const float* wo = (const float*)d_in[30];
    float* out = (float*)d_out;

    // ---- workspace: fp32 tensors + fp64 partials/params + u8 masks (~153 MB) ----
    float* wsf = (float*)d_ws;
    size_t offf = 0;
    auto allocf = [&](size_t n) { float* p = wsf + offf; offf += n; return p; };
    float* R1 = allocf(16777216);
    float* R2 = allocf(16777216);
    float* S1 = allocf(1048576);
    float* S2 = allocf(1048576);
    float* T = allocf(262144);
    double* wsd = (double*)(wsf + offf);
    double* partial = wsd;          // up to 256 blocks x (2*32+1) doubles
    double* params = wsd + 16640;
    u8* wsm = (u8*)(wsd + 16640 + 128);
    size_t offm = 0;
    auto allocm = [&](size_t n) { u8* p = wsm + offm; offm += n; return p; };
    u8* m32 = allocm(4194304);
    u8* m16 = allocm(524288);
    u8* m8 = allocm(65536);
    u8* m4 = allocm(8192);
    u8* mD8 = allocm(65536);
    u8* mD16 = allocm(524288);
    u8* mD32 = allocm(4194304);
    // active-group list: aliases S2 (4 MB; lifetimes disjoint:
    //  glist used [start..convbn4c], decoder lists used in decoder stage 2;
    //  S2 live only [enc stage2 .. dec stage0])
    int* list = (int*)S2;
    int* gcnt = (int*)(wsm + offm);   // 4 bytes past the mask region (as in prior passing round)
    // scan scratch aliases T (1 MB; T live only [enc stage2 down_k .. dec stage0 bn_reduce],
    // builders run before enc stage0 and in dec stage2 — both outside T's live range)
    int* bcnt = (int*)T;              // 4096 ints
    int* boff = bcnt + 4096;          // 4096 ints

    const int N32 = 128 * 32768;
    const int N16 = 128 * 4096;
    const int N8 = 128 * 512;
    const int N4 = 128 * 64;
    const int NG32 = N32 / 4;         // 1048576 groups -> 4096 blocks of 256
    auto gs = [](int n) { return dim3((n + 255) / 256); };
    auto rbn = [](int n) { int bl = (n + 255) / 256; return bl > 256 ? 256 : bl; };
    dim3 blk(256);
    dim3 gblk(NG32 / 256);            // 4096

    // masks
    mask_init_k<<<gs(N32), blk, 0, stream>>>(mraw, m32, N32);
    pool_k<16><<<gs(N16), blk, 0, stream>>>(m32, m16);
    pool_k<8><<<gs(N8), blk, 0, stream>>>(m16, m8);
    pool_k<4><<<gs(N4), blk, 0, stream>>>(m8, m4);

    // ---- encoder stage 0 @32^3, ordered-list-driven on m32 groups ----
    glist_count_k<0><<<gblk, blk, 0, stream>>>(m32, bcnt);
    scan4096_k<<<1, 256, 0, stream>>>(bcnt, boff, gcnt);
    glist_fill_k<0><<<gblk, blk, 0, stream>>>(m32, boff, list);
    prep4c_k<<<gblk, blk, 0, stream>>>(vox, m32, wp, R1, list, gcnt);
    int nb0 = rbn(N32);
    bn_reduce_k<4><<<dim3(nb0), blk, 0, stream>>>(R1, m32, N32, partial);
    bn_final_k<4><<<1, 64, 0, stream>>>(partial, nb0, g_e0, b_e0, params);
    hipMemsetAsync(R2, 0, (size_t)N32 * 4 * sizeof(float), stream);   // down_k reads unmasked
    convbn4c_k<<<gblk, blk, 0, stream>>>(R1, ws_e0, m32, params, R2, list, gcnt);
    down_k<4, 8, 16><<<gs(N16), blk, 0, stream>>>(R2, wd_e0, m16, R1);

    // ---- encoder stage 1 @16^3 ----
    int nb1 = rbn(N16);
    bn_reduce_k<8><<<dim3(nb1), blk, 0, stream>>>(R1, m16, N16, partial);
    bn_final_k<8><<<1, 64, 0, stream>>>(partial, nb1, g_e1, b_e1, params);
    convbn_k<8, 8, 16><<<gs(N16), blk, 0, stream>>>(R1, ws_e1, m16, params, R2);
    down_k<8, 16, 8><<<gs(N8), blk, 0, stream>>>(R2, wd_e1, m8, S1);

    // ---- encoder stage 2 @8^3 ----
    int nb2 = rbn(N8);
    bn_reduce_k<16><<<dim3(nb2), blk, 0, stream>>>(S1, m8, N8, partial);
    bn_final_k<16><<<1, 64, 0, stream>>>(partial, nb2, g_e2, b_e2, params);
    convbn_k<16, 16, 8><<<gs(N8), blk, 0, stream>>>(S1, ws_e2, m8, params, S2);
    down_k<16, 32, 4><<<gs(N4), blk, 0, stream>>>(S2, wd_e2, m4, T);

    // ---- hidden ----
    hidden_k<<<gs(128 * 2048), blk, 0, stream>>>(T, out);

    // ---- decoder stage 0 (32->16, 4^3 -> 8^3), band gate delta=4e-7 ----
    int nb3 = rbn(N4);
    bn_reduce_k<32><<<dim3(nb3), blk, 0, stream>>>(T, m4, N4, partial);
    bn_final_k<32><<<1, 64, 0, stream>>>(partial, nb3, g_d0, b_d0, params);
    upbn_k<32, 16, 4><<<gs(N8), blk, 0, stream>>>(T, wu_d0, m4, params, S1);
    conv3s_k<16, 16, 8><<<gs(N8), blk, 0, stream>>>(S1, ws3_d0, m4, mD8, S2, 4e-7);
    conv_k<4, 16, 16, 8><<<gs(N8), blk, 0, stream>>>(S2, ws4_d0, mD8, S1);

    // ---- decoder stage 1 (16->8, 8^3 -> 16^3), band gate delta=4e-7 ----
    int nb4 = rbn(N8);
    bn_reduce_k<16><<<dim3(nb4), blk, 0, stream>>>(S1, mD8, N8, partial);
    bn_final_k<16><<<1, 64, 0, stream>>>(partial, nb4, g_d1, b_d1, params);
    upbn_k<16, 8, 8><<<gs(N16), blk, 0, stream>>>(S1, wu_d1, mD8, params, R1);
    conv3s_k<8, 8, 16><<<gs(N16), blk, 0, stream>>>(R1, ws3_d1, mD8, mD16, R2, 4e-7);
    conv_k<4, 8, 8, 16><<<gs(N16), blk, 0, stream>>>(R2, ws4_d1, mD16, R1);

    // ---- decoder stage 2 (8->4, 16^3 -> 32^3), exact gate, ordered-list-driven ----
    int nb5 = rbn(N16);
    bn_reduce_k<8><<<dim3(nb5), blk, 0, stream>>>(R1, mD16, N16, partial);
    bn_final_k<8><<<1, 64, 0, stream>>>(partial, nb5, g_d2, b_d2, params);
    upbn_k<8, 4, 16><<<gs(N32), blk, 0, stream>>>(R1, wu_d2, mD16, params, R2);
    // conv3s4: gate = mD16 pairs; pre-zero its outputs (R1 + mD32)
    hipMemsetAsync(R1, 0, (size_t)N32 * 4 * sizeof(float), stream);
    hipMemsetAsync(mD32, 0, (size_t)N32, stream);
    glist_count_k<1><<<gblk, blk, 0, stream>>>(mD16, bcnt);
    scan4096_k<<<1, 256, 0, stream>>>(bcnt, boff, gcnt);
    glist_fill_k<1><<<gblk, blk, 0, stream>>>(mD16, boff, list);
    conv3s4c_k<<<gblk, blk, 0, stream>>>(R2, ws3_d2, mD16, mD32, R1, 0.0, list, gcnt);
    // conv4x4 + outconv: gate = mD32 groups; pre-zero their outputs
    hipMemsetAsync(R2, 0, (size_t)N32 * 4 * sizeof(float), stream);
    glist_count_k<0><<<gblk, blk, 0, stream>>>(mD32, bcnt);
    scan4096_k<<<1, 256, 0, stream>>>(bcnt, boff, gcnt);
    glist_fill_k<0><<<gblk, blk, 0, stream>>>(mD32, boff, list);
    conv4x4c_k<<<gblk, blk, 0, stream>>>(R1, ws4_d2, mD32, R2, list, gcnt);
    hipMemsetAsync(out + 262144, 0, (size_t)N32 * sizeof(float), stream);
    outconv4c_k<<<gblk, blk, 0, stream>>>(R2, wo, mD32, out + 262144, list, gcnt);
}

// Round 3
// 1455.096 us; speedup vs baseline: 1.5313x; 1.1583x over previous
//
#include <hip/hip_runtime.h>

using u8 = unsigned char;

// ---------------- mask init: m = (maskraw == 0) ----------------
__global__ void mask_init_k(const int* __restrict__ mr, u8* __restrict__ m, int N) {
    int i = blockIdx.x * blockDim.x + threadIdx.x;
    if (i < N) m[i] = (mr[i] == 0) ? 1 : 0;
}

// ---------------- mask pool 2x2x2 (logical OR), full batch ----------------
template <int SO>
__global__ void pool_k(const u8* __restrict__ mi, u8* __restrict__ mo) {
    const int N = 128 * SO * SO * SO;
    constexpr int SI = 2 * SO;
    int v = blockIdx.x * blockDim.x + threadIdx.x;
    if (v >= N) return;
    int t = v;
    int x = t % SO; t /= SO;
    int y = t % SO; t /= SO;
    int z = t % SO;
    int n = t / SO;
    u8 m = 0;
    for (int kd = 0; kd < 2; kd++)
        for (int kh = 0; kh < 2; kh++)
            for (int kw = 0; kw < 2; kw++)
                m |= mi[((n * SI + 2 * z + kd) * SI + 2 * y + kh) * SI + 2 * x + kw];
    mo[v] = m;
}

// ================= 32^3 LDS-tiled kernels =================
// Block = 256 threads, tile X=32 (8 groups of 4), Y=8, Z=4 outputs.
// Grid 4096: ty=bid&3 (y0=ty*8), tz=(bid>>2)&7 (z0=tz*4), n=bid>>5.
// Input halo staged to LDS with zero-padded borders; x padded to 35 slots (x_ = gx+1)
// so compute reads need no bounds checks. Row stride 35 (f4) => 12-bank offset/row,
// conflict-light for the 8-row x 8-xg wave access pattern.
// Outputs written DENSE (mask-gated values, zeros elsewhere) -> no memsets, no lists.
// FP op order per output voxel identical to prior passing kernel (zero-halo terms are
// exact fma(0,w,acc) no-ops).

// ---------------- prepare conv 1->4, k=3 (input masked at stage-in) ----------------
__global__ void prep4t_k(const float* __restrict__ vox, const u8* __restrict__ m,
                         const float* __restrict__ wp, float* __restrict__ out) {
    __shared__ float til[6 * 10 * 35];   // [zz][yy][x_], 8.4 KB
    int bid = blockIdx.x;
    int y0 = (bid & 3) << 3, z0 = ((bid >> 2) & 7) << 2, n = bid >> 5;
    for (int t = threadIdx.x; t < 6 * 10 * 35; t += 256) {
        int x_ = t % 35;
        int rr = t / 35;
        int yy = rr % 10, zz = rr / 10;
        int gx = x_ - 1, gy = y0 + yy - 1, gz = z0 + zz - 1;
        float v = 0.f;
        if ((unsigned)gx < 32u && (unsigned)gy < 32u && (unsigned)gz < 32u) {
            int gi = ((n * 32 + gz) * 32 + gy) * 32 + gx;
            if (m[gi]) v = vox[gi];
        }
        til[t] = v;
    }
    __syncthreads();
    int tx = threadIdx.x;
    int xg = tx & 7, ly = (tx >> 3) & 7, lz = tx >> 6;
    int xb = xg << 2;
    int vbase = ((n * 32 + z0 + lz) * 32 + y0 + ly) * 32 + xb;
    u8 om[4];
#pragma unroll
    for (int j = 0; j < 4; j++) om[j] = m[vbase + j];
    float acc[4][4];
#pragma unroll
    for (int j = 0; j < 4; j++)
#pragma unroll
        for (int co = 0; co < 4; co++) acc[j][co] = 0.f;
    for (int kd = 0; kd < 3; kd++) {
        for (int kh = 0; kh < 3; kh++) {
            const float* rowp = &til[((lz + kd) * 10 + ly + kh) * 35 + xb];
            float col[6];
#pragma unroll
            for (int c = 0; c < 6; c++) col[c] = rowp[c];
            const float* wrow = wp + ((kd * 3 + kh) * 3) * 4;
#pragma unroll
            for (int kw = 0; kw < 3; kw++) {
                const float* wt = wrow + kw * 4;
#pragma unroll
                for (int j = 0; j < 4; j++) {
                    float xv = col[j + kw];
#pragma unroll
                    for (int co = 0; co < 4; co++) acc[j][co] += xv * wt[co];
                }
            }
        }
    }
#pragma unroll
    for (int j = 0; j < 4; j++)
#pragma unroll
        for (int co = 0; co < 4; co++)
            out[(size_t)(vbase + j) * 4 + co] = om[j] ? acc[j][co] : 0.f;
}

// ---------------- conv k=3, 4->4, BN(affine+ReLU+mask) applied at stage-in ----------------
__global__ void convbn4t_k(const float* __restrict__ in, const float* __restrict__ w,
                           const u8* __restrict__ mask, const double* __restrict__ params,
                           float* __restrict__ out) {
    __shared__ float4 til[6 * 10 * 35];  // 33.6 KB
    float sc[4], sh[4];
#pragma unroll
    for (int c = 0; c < 4; c++) { sc[c] = (float)params[c]; sh[c] = (float)params[4 + c]; }
    int bid = blockIdx.x;
    int y0 = (bid & 3) << 3, z0 = ((bid >> 2) & 7) << 2, n = bid >> 5;
    for (int t = threadIdx.x; t < 6 * 10 * 35; t += 256) {
        int x_ = t % 35;
        int rr = t / 35;
        int yy = rr % 10, zz = rr / 10;
        int gx = x_ - 1, gy = y0 + yy - 1, gz = z0 + zz - 1;
        float4 v = make_float4(0.f, 0.f, 0.f, 0.f);
        if ((unsigned)gx < 32u && (unsigned)gy < 32u && (unsigned)gz < 32u) {
            int gi = ((n * 32 + gz) * 32 + gy) * 32 + gx;
            if (mask[gi]) {
                float4 r = *(const float4*)(in + (size_t)gi * 4);
                v.x = fmaxf(r.x * sc[0] + sh[0], 0.f);
                v.y = fmaxf(r.y * sc[1] + sh[1], 0.f);
                v.z = fmaxf(r.z * sc[2] + sh[2], 0.f);
                v.w = fmaxf(r.w * sc[3] + sh[3], 0.f);
            }
        }
        til[t] = v;
    }
    __syncthreads();
    int tx = threadIdx.x;
    int xg = tx & 7, ly = (tx >> 3) & 7, lz = tx >> 6;
    int xb = xg << 2;
    int vbase = ((n * 32 + z0 + lz) * 32 + y0 + ly) * 32 + xb;
    u8 om[4];
#pragma unroll
    for (int j = 0; j < 4; j++) om[j] = mask[vbase + j];
    float acc[4][4];
#pragma unroll
    for (int j = 0; j < 4; j++)
#pragma unroll
        for (int co = 0; co < 4; co++) acc[j][co] = 0.f;
    for (int kd = 0; kd < 3; kd++) {
        for (int kh = 0; kh < 3; kh++) {
            const float4* rowp = &til[((lz + kd) * 10 + ly + kh) * 35 + xb];
            float col[6][4];
#pragma unroll
            for (int c = 0; c < 6; c++) {
                float4 t4 = rowp[c];
                col[c][0] = t4.x; col[c][1] = t4.y; col[c][2] = t4.z; col[c][3] = t4.w;
            }
            const float* wrow = w + ((kd * 3 + kh) * 3) * 16;
#pragma unroll
            for (int kw = 0; kw < 3; kw++) {
                const float* wt = wrow + kw * 16;
#pragma unroll
                for (int j = 0; j < 4; j++) {
#pragma unroll
                    for (int ci = 0; ci < 4; ci++) {
                        float xv = col[j + kw][ci];
#pragma unroll
                        for (int co = 0; co < 4; co++) acc[j][co] += xv * wt[ci * 4 + co];
                    }
                }
            }
        }
    }
#pragma unroll
    for (int j = 0; j < 4; j++)
#pragma unroll
        for (int co = 0; co < 4; co++)
            out[(size_t)(vbase + j) * 4 + co] = om[j] ? acc[j][co] : 0.f;
}

// ---------------- conv k=3 4->4 + fused sparsify (fp64 gate) ----------------
__global__ void conv3s4t_k(const float* __restrict__ in, const float* __restrict__ w,
                           const u8* __restrict__ pmask, u8* __restrict__ nmask,
                           float* __restrict__ out, double delta) {
    __shared__ float4 til[6 * 10 * 35];  // 33.6 KB
    int bid = blockIdx.x;
    int y0 = (bid & 3) << 3, z0 = ((bid >> 2) & 7) << 2, n = bid >> 5;
    for (int t = threadIdx.x; t < 6 * 10 * 35; t += 256) {
        int x_ = t % 35;
        int rr = t / 35;
        int yy = rr % 10, zz = rr / 10;
        int gx = x_ - 1, gy = y0 + yy - 1, gz = z0 + zz - 1;
        float4 v = make_float4(0.f, 0.f, 0.f, 0.f);
        if ((unsigned)gx < 32u && (unsigned)gy < 32u && (unsigned)gz < 32u)
            v = *(const float4*)(in + (size_t)(((n * 32 + gz) * 32 + gy) * 32 + gx) * 4);
        til[t] = v;
    }
    __syncthreads();
    int tx = threadIdx.x;
    int xg = tx & 7, ly = (tx >> 3) & 7, lz = tx >> 6;
    int xb = xg << 2;
    int gy = y0 + ly, gz = z0 + lz;
    int vbase = ((n * 32 + gz) * 32 + gy) * 32 + xb;
    int pbase = ((n * 16 + (gz >> 1)) * 16 + (gy >> 1)) * 16 + (xb >> 1);
    u8 pm[4];
    pm[0] = pm[1] = pmask[pbase];
    pm[2] = pm[3] = pmask[pbase + 1];
    double acc0[4], asum[4];
    float accf[4][4];
#pragma unroll
    for (int j = 0; j < 4; j++) {
        acc0[j] = 0.0; asum[j] = 0.0;
#pragma unroll
        for (int co = 0; co < 4; co++) accf[j][co] = 0.f;
    }
    for (int kd = 0; kd < 3; kd++) {
        for (int kh = 0; kh < 3; kh++) {
            const float4* rowp = &til[((lz + kd) * 10 + ly + kh) * 35 + xb];
            float col[6][4];
#pragma unroll
            for (int c = 0; c < 6; c++) {
                float4 t4 = rowp[c];
                col[c][0] = t4.x; col[c][1] = t4.y; col[c][2] = t4.z; col[c][3] = t4.w;
            }
            const float* wrow = w + ((kd * 3 + kh) * 3) * 16;
#pragma unroll
            for (int kw = 0; kw < 3; kw++) {
                const float* wt = wrow + kw * 16;
#pragma unroll
                for (int j = 0; j < 4; j++) {
#pragma unroll
                    for (int ci = 0; ci < 4; ci++) {
                        float xv = col[j + kw][ci];
                        double term = (double)xv * (double)wt[ci * 4 + 0];
                        acc0[j] += term;
                        asum[j] += fabs(term);
#pragma unroll
                        for (int co = 1; co < 4; co++) accf[j][co] += xv * wt[ci * 4 + co];
                    }
                }
            }
        }
    }
#pragma unroll
    for (int j = 0; j < 4; j++) {
        u8 nm = (pm[j] && (acc0[j] > -delta * asum[j])) ? 1 : 0;
        nmask[vbase + j] = nm;
        out[(size_t)(vbase + j) * 4 + 0] = nm ? (float)acc0[j] : 0.f;
#pragma unroll
        for (int co = 1; co < 4; co++) out[(size_t)(vbase + j) * 4 + co] = nm ? accf[j][co] : 0.f;
    }
}

// ---------------- plain conv 4->4, k=4 pad(1,2) ----------------
__global__ void conv4x4t_k(const float* __restrict__ in, const float* __restrict__ w,
                           const u8* __restrict__ outmask, float* __restrict__ out) {
    __shared__ float4 til[7 * 11 * 35];  // 43.1 KB
    int bid = blockIdx.x;
    int y0 = (bid & 3) << 3, z0 = ((bid >> 2) & 7) << 2, n = bid >> 5;
    for (int t = threadIdx.x; t < 7 * 11 * 35; t += 256) {
        int x_ = t % 35;
        int rr = t / 35;
        int yy = rr % 11, zz = rr / 11;
        int gx = x_ - 1, gy = y0 + yy - 1, gz = z0 + zz - 1;
        float4 v = make_float4(0.f, 0.f, 0.f, 0.f);
        if ((unsigned)gx < 32u && (unsigned)gy < 32u && (unsigned)gz < 32u)
            v = *(const float4*)(in + (size_t)(((n * 32 + gz) * 32 + gy) * 32 + gx) * 4);
        til[t] = v;
    }
    __syncthreads();
    int tx = threadIdx.x;
    int xg = tx & 7, ly = (tx >> 3) & 7, lz = tx >> 6;
    int xb = xg << 2;
    int vbase = ((n * 32 + z0 + lz) * 32 + y0 + ly) * 32 + xb;
    u8 om[4];
#pragma unroll
    for (int j = 0; j < 4; j++) om[j] = outmask[vbase + j];
    float acc[4][4];
#pragma unroll
    for (int j = 0; j < 4; j++)
#pragma unroll
        for (int co = 0; co < 4; co++) acc[j][co] = 0.f;
    for (int kd = 0; kd < 4; kd++) {
        for (int kh = 0; kh < 4; kh++) {
            const float4* rowp = &til[((lz + kd) * 11 + ly + kh) * 35 + xb];
            float col[7][4];
#pragma unroll
            for (int c = 0; c < 7; c++) {
                float4 t4 = rowp[c];
                col[c][0] = t4.x; col[c][1] = t4.y; col[c][2] = t4.z; col[c][3] = t4.w;
            }
            const float* wrow = w + ((kd * 4 + kh) * 4) * 16;
#pragma unroll
            for (int kw = 0; kw < 4; kw++) {
                const float* wt = wrow + kw * 16;
#pragma unroll
                for (int j = 0; j < 4; j++) {
#pragma unroll
                    for (int ci = 0; ci < 4; ci++) {
                        float xv = col[j + kw][ci];
#pragma unroll
                        for (int co = 0; co < 4; co++) acc[j][co] += xv * wt[ci * 4 + co];
                    }
                }
            }
        }
    }
#pragma unroll
    for (int j = 0; j < 4; j++)
#pragma unroll
        for (int co = 0; co < 4; co++)
            out[(size_t)(vbase + j) * 4 + co] = om[j] ? acc[j][co] : 0.f;
}

// ---------------- final output conv k=3, 4->1 ----------------
__global__ void outconv4t_k(const float* __restrict__ in, const float* __restrict__ w,
                            const u8* __restrict__ mask, float* __restrict__ out) {
    __shared__ float4 til[6 * 10 * 35];  // 33.6 KB
    int bid = blockIdx.x;
    int y0 = (bid & 3) << 3, z0 = ((bid >> 2) & 7) << 2, n = bid >> 5;
    for (int t = threadIdx.x; t < 6 * 10 * 35; t += 256) {
        int x_ = t % 35;
        int rr = t / 35;
        int yy = rr % 10, zz = rr / 10;
        int gx = x_ - 1, gy = y0 + yy - 1, gz = z0 + zz - 1;
        float4 v = make_float4(0.f, 0.f, 0.f, 0.f);
        if ((unsigned)gx < 32u && (unsigned)gy < 32u && (unsigned)gz < 32u)
            v = *(const float4*)(in + (size_t)(((n * 32 + gz) * 32 + gy) * 32 + gx) * 4);
        til[t] = v;
    }
    __syncthreads();
    int tx = threadIdx.x;
    int xg = tx & 7, ly = (tx >> 3) & 7, lz = tx >> 6;
    int xb = xg << 2;
    int vbase = ((n * 32 + z0 + lz) * 32 + y0 + ly) * 32 + xb;
    u8 om[4];
#pragma unroll
    for (int j = 0; j < 4; j++) om[j] = mask[vbase + j];
    float acc[4] = {0.f, 0.f, 0.f, 0.f};
    for (int kd = 0; kd < 3; kd++) {
        for (int kh = 0; kh < 3; kh++) {
            const float4* rowp = &til[((lz + kd) * 10 + ly + kh) * 35 + xb];
            float col[6][4];
#pragma unroll
            for (int c = 0; c < 6; c++) {
                float4 t4 = rowp[c];
                col[c][0] = t4.x; col[c][1] = t4.y; col[c][2] = t4.z; col[c][3] = t4.w;
            }
            const float* wrow = w + ((kd * 3 + kh) * 3) * 4;
#pragma unroll
            for (int kw = 0; kw < 3; kw++) {
                const float* wt = wrow + kw * 4;
#pragma unroll
                for (int j = 0; j < 4; j++) {
#pragma unroll
                    for (int ci = 0; ci < 4; ci++) acc[j] += col[j + kw][ci] * wt[ci];
                }
            }
        }
    }
#pragma unroll
    for (int j = 0; j < 4; j++) out[vbase + j] = om[j] ? acc[j] : 0.f;
}

// ================= generic kernels for 16^3 / 8^3 stages (unchanged) =================

template <int K, int CIN, int COUT, int S>
__global__ void conv_k(const float* __restrict__ in, const float* __restrict__ w,
                       const u8* __restrict__ outmask, float* __restrict__ out) {
    const int N = 128 * S * S * S;
    int v = blockIdx.x * blockDim.x + threadIdx.x;
    if (v >= N) return;
    if (!outmask[v]) {
#pragma unroll
        for (int co = 0; co < COUT; co++) out[(size_t)v * COUT + co] = 0.f;
        return;
    }
    int t = v;
    int x = t % S; t /= S;
    int y = t % S; t /= S;
    int z = t % S;
    int n = t / S;
    float acc[COUT];
#pragma unroll
    for (int co = 0; co < COUT; co++) acc[co] = 0.f;
    constexpr int PLO = (K - 1) / 2;
    for (int kd = 0; kd < K; kd++) {
        int zz = z + kd - PLO; if ((unsigned)zz >= (unsigned)S) continue;
        for (int kh = 0; kh < K; kh++) {
            int yy = y + kh - PLO; if ((unsigned)yy >= (unsigned)S) continue;
            for (int kw = 0; kw < K; kw++) {
                int xx = x + kw - PLO; if ((unsigned)xx >= (unsigned)S) continue;
                int sv = ((n * S + zz) * S + yy) * S + xx;
                const float* ip = in + (size_t)sv * CIN;
                const float* wpk = w + ((kd * K + kh) * K + kw) * CIN * COUT;
#pragma unroll
                for (int ci = 0; ci < CIN; ci++) {
                    float xv = ip[ci];
#pragma unroll
                    for (int co = 0; co < COUT; co++) acc[co] += xv * wpk[ci * COUT + co];
                }
            }
        }
    }
#pragma unroll
    for (int co = 0; co < COUT; co++) out[(size_t)v * COUT + co] = acc[co];
}

template <int CIN, int COUT, int S>
__global__ void convbn_k(const float* __restrict__ in, const float* __restrict__ w,
                         const u8* __restrict__ mask, const double* __restrict__ params,
                         float* __restrict__ out) {
    const int N = 128 * S * S * S;
    int v = blockIdx.x * blockDim.x + threadIdx.x;
    if (v >= N) return;
    if (!mask[v]) {
#pragma unroll
        for (int co = 0; co < COUT; co++) out[(size_t)v * COUT + co] = 0.f;
        return;
    }
    int t = v;
    int x = t % S; t /= S;
    int y = t % S; t /= S;
    int z = t % S;
    int n = t / S;
    float sc[CIN], sh[CIN];
#pragma unroll
    for (int c = 0; c < CIN; c++) { sc[c] = (float)params[c]; sh[c] = (float)params[CIN + c]; }
    float acc[COUT];
#pragma unroll
    for (int co = 0; co < COUT; co++) acc[co] = 0.f;
    for (int kd = 0; kd < 3; kd++) {
        int zz = z + kd - 1; if ((unsigned)zz >= (unsigned)S) continue;
        for (int kh = 0; kh < 3; kh++) {
            int yy = y + kh - 1; if ((unsigned)yy >= (unsigned)S) continue;
            for (int kw = 0; kw < 3; kw++) {
                int xx = x + kw - 1; if ((unsigned)xx >= (unsigned)S) continue;
                int sv = ((n * S + zz) * S + yy) * S + xx;
                if (!mask[sv]) continue;
                const float* ip = in + (size_t)sv * CIN;
                const float* wpk = w + ((kd * 3 + kh) * 3 + kw) * CIN * COUT;
#pragma unroll
                for (int ci = 0; ci < CIN; ci++) {
                    float yv = fmaxf(ip[ci] * sc[ci] + sh[ci], 0.f);
#pragma unroll
                    for (int co = 0; co < COUT; co++) acc[co] += yv * wpk[ci * COUT + co];
                }
            }
        }
    }
#pragma unroll
    for (int co = 0; co < COUT; co++) out[(size_t)v * COUT + co] = acc[co];
}

template <int CIN, int COUT, int S>
__global__ void conv3s_k(const float* __restrict__ in, const float* __restrict__ w,
                         const u8* __restrict__ pmask, u8* __restrict__ nmask,
                         float* __restrict__ out, double delta) {
    const int N = 128 * S * S * S;
    constexpr int SP = S / 2;
    int v = blockIdx.x * blockDim.x + threadIdx.x;
    if (v >= N) return;
    int t = v;
    int x = t % S; t /= S;
    int y = t % S; t /= S;
    int z = t % S;
    int n = t / S;
    int pidx = ((n * SP + (z >> 1)) * SP + (y >> 1)) * SP + (x >> 1);
    if (!pmask[pidx]) {
        nmask[v] = 0;
#pragma unroll
        for (int co = 0; co < COUT; co++) out[(size_t)v * COUT + co] = 0.f;
        return;
    }
    double acc0 = 0.0, asum = 0.0;
    float acc[COUT];
#pragma unroll
    for (int co = 0; co < COUT; co++) acc[co] = 0.f;
    for (int kd = 0; kd < 3; kd++) {
        int zz = z + kd - 1; if ((unsigned)zz >= (unsigned)S) continue;
        for (int kh = 0; kh < 3; kh++) {
            int yy = y + kh - 1; if ((unsigned)yy >= (unsigned)S) continue;
            for (int kw = 0; kw < 3; kw++) {
                int xx = x + kw - 1; if ((unsigned)xx >= (unsigned)S) continue;
                int sv = ((n * S + zz) * S + yy) * S + xx;
                const float* ip = in + (size_t)sv * CIN;
                const float* wpk = w + ((kd * 3 + kh) * 3 + kw) * CIN * COUT;
#pragma unroll
                for (int ci = 0; ci < CIN; ci++) {
                    float xv = ip[ci];
                    double term = (double)xv * (double)wpk[ci * COUT + 0];
                    acc0 += term;
                    asum += fabs(term);
#pragma unroll
                    for (int co = 1; co < COUT; co++) acc[co] += xv * wpk[ci * COUT + co];
                }
            }
        }
    }
    u8 nm = (acc0 > -delta * asum) ? 1 : 0;
    nmask[v] = nm;
    out[(size_t)v * COUT + 0] = nm ? (float)acc0 : 0.f;
#pragma unroll
    for (int co = 1; co < COUT; co++) out[(size_t)v * COUT + co] = nm ? acc[co] : 0.f;
}

template <int CIN, int COUT, int SO>
__global__ void down_k(const float* __restrict__ in, const float* __restrict__ w,
                       const u8* __restrict__ outmask, float* __restrict__ out) {
    const int N = 128 * SO * SO * SO;
    constexpr int SI = 2 * SO;
    int v = blockIdx.x * blockDim.x + threadIdx.x;
    if (v >= N) return;
    if (!outmask[v]) {
#pragma unroll
        for (int co = 0; co < COUT; co++) out[(size_t)v * COUT + co] = 0.f;
        return;
    }
    int t = v;
    int x = t % SO; t /= SO;
    int y = t % SO; t /= SO;
    int z = t % SO;
    int n = t / SO;
    float acc[COUT];
#pragma unroll
    for (int co = 0; co < COUT; co++) acc[co] = 0.f;
    for (int kd = 0; kd < 2; kd++)
        for (int kh = 0; kh < 2; kh++)
            for (int kw = 0; kw < 2; kw++) {
                int sv = ((n * SI + 2 * z + kd) * SI + 2 * y + kh) * SI + 2 * x + kw;
                const float* ip = in + (size_t)sv * CIN;
                const float* wpk = w + ((kd * 2 + kh) * 2 + kw) * CIN * COUT;
#pragma unroll
                for (int ci = 0; ci < CIN; ci++) {
                    float xv = ip[ci];
#pragma unroll
                    for (int co = 0; co < COUT; co++) acc[co] += xv * wpk[ci * COUT + co];
                }
            }
#pragma unroll
    for (int co = 0; co < COUT; co++) out[(size_t)v * COUT + co] = acc[co];
}

template <int CIN, int COUT, int SI>
__global__ void upbn_k(const float* __restrict__ in, const float* __restrict__ w,
                       const u8* __restrict__ inmask, const double* __restrict__ params,
                       float* __restrict__ out) {
    constexpr int SO = 2 * SI;
    const int N = 128 * SO * SO * SO;
    int v = blockIdx.x * blockDim.x + threadIdx.x;
    if (v >= N) return;
    int t = v;
    int x = t % SO; t /= SO;
    int y = t % SO; t /= SO;
    int z = t % SO;
    int n = t / SO;
    int sv = ((n * SI + (z >> 1)) * SI + (y >> 1)) * SI + (x >> 1);
    if (!inmask[sv]) {
#pragma unroll
        for (int co = 0; co < COUT; co++) out[(size_t)v * COUT + co] = 0.f;
        return;
    }
    int tap = ((1 - (z & 1)) * 2 + (1 - (y & 1))) * 2 + (1 - (x & 1));
    const float* wpk = w + tap * CIN * COUT;
    const float* ip = in + (size_t)sv * CIN;
    float acc[COUT];
#pragma unroll
    for (int co = 0; co < COUT; co++) acc[co] = 0.f;
#pragma unroll
    for (int ci = 0; ci < CIN; ci++) {
        float yv = fmaxf(ip[ci] * (float)params[ci] + (float)params[CIN + ci], 0.f);
#pragma unroll
        for (int co = 0; co < COUT; co++) acc[co] += yv * wpk[ci * COUT + co];
    }
#pragma unroll
    for (int co = 0; co < COUT; co++) out[(size_t)v * COUT + co] = acc[co];
}

// ---------------- BN masked reduce, DETERMINISTIC two-pass: per-block partials ----------------
template <int C>
__global__ void bn_reduce_k(const float* __restrict__ x, const u8* __restrict__ m, int N,
                            double* __restrict__ partial) {
    double cnt = 0.0, sx[C], s2[C];
#pragma unroll
    for (int c = 0; c < C; c++) { sx[c] = 0.0; s2[c] = 0.0; }
    int stride = gridDim.x * blockDim.x;
    for (int v = blockIdx.x * blockDim.x + threadIdx.x; v < N; v += stride) {
        if (!m[v]) continue;
        cnt += 1.0;
#pragma unroll
        for (int c = 0; c < C; c++) {
            double xv = (double)x[(size_t)v * C + c];
            sx[c] += xv;
            s2[c] += xv * xv;
        }
    }
#pragma unroll
    for (int off = 32; off > 0; off >>= 1) {
        cnt += __shfl_down(cnt, off, 64);
#pragma unroll
        for (int c = 0; c < C; c++) {
            sx[c] += __shfl_down(sx[c], off, 64);
            s2[c] += __shfl_down(s2[c], off, 64);
        }
    }
    __shared__ double sbuf[4][2 * C + 1];
    int wave = threadIdx.x >> 6;
    if ((threadIdx.x & 63) == 0) {
        sbuf[wave][0] = cnt;
#pragma unroll
        for (int c = 0; c < C; c++) {
            sbuf[wave][1 + c] = sx[c];
            sbuf[wave][1 + C + c] = s2[c];
        }
    }
    __syncthreads();
    if (threadIdx.x == 0) {
        double* p = partial + (size_t)blockIdx.x * (2 * C + 1);
        double tcnt = 0.0;
        for (int wv = 0; wv < 4; wv++) tcnt += sbuf[wv][0];
        p[0] = tcnt;
#pragma unroll
        for (int c = 0; c < C; c++) {
            double a = 0.0, b = 0.0;
            for (int wv = 0; wv < 4; wv++) { a += sbuf[wv][1 + c]; b += sbuf[wv][1 + C + c]; }
            p[1 + c] = a;
            p[1 + C + c] = b;
        }
    }
}

// ---------------- BN finalize: fixed-order sum of block partials ----------------
template <int C>
__global__ void bn_final_k(const double* __restrict__ partial, int nblocks,
                           const float* __restrict__ g, const float* __restrict__ b,
                           double* __restrict__ params) {
    int c = threadIdx.x;
    if (c >= C) return;
    double cnt = 0.0, sx = 0.0, s2 = 0.0;
    for (int bk = 0; bk < nblocks; bk++) {
        const double* p = partial + (size_t)bk * (2 * C + 1);
        cnt += p[0];
        sx += p[1 + c];
        s2 += p[1 + C + c];
    }
    if (cnt < 1.0) cnt = 1.0;
    double mean = sx / cnt;
    double var = s2 / cnt - mean * mean;
    double sc = (double)g[c] / sqrt(var + 1e-4);
    params[c] = sc;
    params[C + c] = (double)b[c] - mean * sc;
}

// ---------------- hidden: NDHWC (4^3, 32ch) -> NCDHW flat ----------------
__global__ void hidden_k(const float* __restrict__ x, float* __restrict__ out) {
    int i = blockIdx.x * blockDim.x + threadIdx.x;
    if (i >= 128 * 2048) return;
    int b = i >> 11;
    int r = i & 2047;
    int c = r >> 6;
    int s = r & 63;
    int d = s >> 4;
    int h = (s >> 2) & 3;
    int w = s & 3;
    out[i] = x[((((b * 4 + d) * 4 + h) * 4 + w) << 5) + c];
}

extern "C" void kernel_launch(void* const* d_in, const int* in_sizes, int n_in,
                              void* d_out, int out_size, void* d_ws, size_t ws_size,
                              hipStream_t stream) {
    const float* vox = (const float*)d_in[0];
    const int* mraw = (const int*)d_in[1];
    const float* wp = (const float*)d_in[2];
    const float* g_e0 = (const float*)d_in[3];
    const float* b_e0 = (const float*)d_in[4];
    const float* ws_e0 = (const float*)d_in[5];
    const float* wd_e0 = (const float*)d_in[6];
    const float* g_e1 = (const float*)d_in[7];
    const float* b_e1 = (const float*)d_in[8];
    const float* ws_e1 = (const float*)d_in[9];
    const float* wd_e1 = (const float*)d_in[10];
    const float* g_e2 = (const float*)d_in[11];
    const float* b_e2 = (const float*)d_in[12];
    const float* ws_e2 = (const float*)d_in[13];
    const float* wd_e2 = (const float*)d_in[14];
    const float* g_d0 = (const float*)d_in[15];
    const float* b_d0 = (const float*)d_in[16];
    const float* wu_d0 = (const float*)d_in[17];
    const float* ws3_d0 = (const float*)d_in[18];
    const float* ws4_d0 = (const float*)d_in[19];
    const float* g_d1 = (const float*)d_in[20];
    const float* b_d1 = (const float*)d_in[21];
    const float* wu_d1 = (const float*)d_in[22];
    const float* ws3_d1 = (const float*)d_in[23];
    const float* ws4_d1 = (const float*)d_in[24];
    const float* g_d2 = (const float*)d_in[25];
    const float* b_d2 = (const float*)d_in[26];
    const float* wu_d2 = (const float*)d_in[27];
    const float* ws3_d2 = (const float*)d_in[28];
    const float* ws4_d2 = (const float*)d_in[29];
    const float* wo = (const float*)d_in[30];
    float* out = (float*)d_out;

    // ---- workspace: fp32 tensors + fp64 partials/params + u8 masks (~153 MB) ----
    float* wsf = (float*)d_ws;
    size_t offf = 0;
    auto allocf = [&](size_t n) { float* p = wsf + offf; offf += n; return p; };
    float* R1 = allocf(16777216);
    float* R2 = allocf(16777216);
    float* S1 = allocf(1048576);
    float* S2 = allocf(1048576);
    float* T = allocf(262144);
    double* wsd = (double*)(wsf + offf);
    double* partial = wsd;          // up to 256 blocks x (2*32+1) doubles
    double* params = wsd + 16640;
    u8* wsm = (u8*)(wsd + 16640 + 128);
    size_t offm = 0;
    auto allocm = [&](size_t n) { u8* p = wsm + offm; offm += n; return p; };
    u8* m32 = allocm(4194304);
    u8* m16 = allocm(524288);
    u8* m8 = allocm(65536);
    u8* m4 = allocm(8192);
    u8* mD8 = allocm(65536);
    u8* mD16 = allocm(524288);
    u8* mD32 = allocm(4194304);

    const int N32 = 128 * 32768;
    const int N16 = 128 * 4096;
    const int N8 = 128 * 512;
    const int N4 = 128 * 64;
    auto gs = [](int n) { return dim3((n + 255) / 256); };
    auto rbn = [](int n) { int bl = (n + 255) / 256; return bl > 256 ? 256 : bl; };
    dim3 blk(256);
    dim3 tgrid(4096);               // 128 images x 4 y-tiles x 8 z-tiles

    // masks
    mask_init_k<<<gs(N32), blk, 0, stream>>>(mraw, m32, N32);
    pool_k<16><<<gs(N16), blk, 0, stream>>>(m32, m16);
    pool_k<8><<<gs(N8), blk, 0, stream>>>(m16, m8);
    pool_k<4><<<gs(N4), blk, 0, stream>>>(m8, m4);

    // ---- encoder stage 0 @32^3, LDS-tiled dense ----
    prep4t_k<<<tgrid, blk, 0, stream>>>(vox, m32, wp, R1);
    int nb0 = rbn(N32);
    bn_reduce_k<4><<<dim3(nb0), blk, 0, stream>>>(R1, m32, N32, partial);
    bn_final_k<4><<<1, 64, 0, stream>>>(partial, nb0, g_e0, b_e0, params);
    convbn4t_k<<<tgrid, blk, 0, stream>>>(R1, ws_e0, m32, params, R2);
    down_k<4, 8, 16><<<gs(N16), blk, 0, stream>>>(R2, wd_e0, m16, R1);

    // ---- encoder stage 1 @16^3 ----
    int nb1 = rbn(N16);
    bn_reduce_k<8><<<dim3(nb1), blk, 0, stream>>>(R1, m16, N16, partial);
    bn_final_k<8><<<1, 64, 0, stream>>>(partial, nb1, g_e1, b_e1, params);
    convbn_k<8, 8, 16><<<gs(N16), blk, 0, stream>>>(R1, ws_e1, m16, params, R2);
    down_k<8, 16, 8><<<gs(N8), blk, 0, stream>>>(R2, wd_e1, m8, S1);

    // ---- encoder stage 2 @8^3 ----
    int nb2 = rbn(N8);
    bn_reduce_k<16><<<dim3(nb2), blk, 0, stream>>>(S1, m8, N8, partial);
    bn_final_k<16><<<1, 64, 0, stream>>>(partial, nb2, g_e2, b_e2, params);
    convbn_k<16, 16, 8><<<gs(N8), blk, 0, stream>>>(S1, ws_e2, m8, params, S2);
    down_k<16, 32, 4><<<gs(N4), blk, 0, stream>>>(S2, wd_e2, m4, T);

    // ---- hidden ----
    hidden_k<<<gs(128 * 2048), blk, 0, stream>>>(T, out);

    // ---- decoder stage 0 (32->16, 4^3 -> 8^3), band gate delta=4e-7 ----
    int nb3 = rbn(N4);
    bn_reduce_k<32><<<dim3(nb3), blk, 0, stream>>>(T, m4, N4, partial);
    bn_final_k<32><<<1, 64, 0, stream>>>(partial, nb3, g_d0, b_d0, params);
    upbn_k<32, 16, 4><<<gs(N8), blk, 0, stream>>>(T, wu_d0, m4, params, S1);
    conv3s_k<16, 16, 8><<<gs(N8), blk, 0, stream>>>(S1, ws3_d0, m4, mD8, S2, 4e-7);
    conv_k<4, 16, 16, 8><<<gs(N8), blk, 0, stream>>>(S2, ws4_d0, mD8, S1);

    // ---- decoder stage 1 (16->8, 8^3 -> 16^3), band gate delta=4e-7 ----
    int nb4 = rbn(N8);
    bn_reduce_k<16><<<dim3(nb4), blk, 0, stream>>>(S1, mD8, N8, partial);
    bn_final_k<16><<<1, 64, 0, stream>>>(partial, nb4, g_d1, b_d1, params);
    upbn_k<16, 8, 8><<<gs(N16), blk, 0, stream>>>(S1, wu_d1, mD8, params, R1);
    conv3s_k<8, 8, 16><<<gs(N16), blk, 0, stream>>>(R1, ws3_d1, mD8, mD16, R2, 4e-7);
    conv_k<4, 8, 8, 16><<<gs(N16), blk, 0, stream>>>(R2, ws4_d1, mD16, R1);

    // ---- decoder stage 2 (8->4, 16^3 -> 32^3), exact gate, LDS-tiled dense ----
    int nb5 = rbn(N16);
    bn_reduce_k<8><<<dim3(nb5), blk, 0, stream>>>(R1, mD16, N16, partial);
    bn_final_k<8><<<1, 64, 0, stream>>>(partial, nb5, g_d2, b_d2, params);
    upbn_k<8, 4, 16><<<gs(N32), blk, 0, stream>>>(R1, wu_d2, mD16, params, R2);
    conv3s4t_k<<<tgrid, blk, 0, stream>>>(R2, ws3_d2, mD16, mD32, R1, 0.0);
    conv4x4t_k<<<tgrid, blk, 0, stream>>>(R1, ws4_d2, mD32, R2);
    outconv4t_k<<<tgrid, blk, 0, stream>>>(R2, wo, mD32, out + 262144);
}